// Round 1
// baseline (1140.637 us; speedup 1.0000x reference)
//
#include <hip/hip_runtime.h>

// Problem constants (B=16, DIM=256, H=W=56, NH=8, HD=32, WS=7)
#define BATCH 16
#define DIM 256
#define HH 56
#define WW 56
#define HWP 3136            // 56*56
#define M_TOT 50176         // BATCH*HWP
#define NQKV 768            // 3*DIM
#define NHEADS 8
#define HDIM 32
#define NWIN 49             // 7*7
#define QKV_BYTES 154140672ull  // M_TOT*NQKV*4

// ---------------------------------------------------------------------------
// Kernel A: qkv = x^T @ qkv_w + qkv_b
// x is (B, C=256, HW) so A^T[k, m] is contiguous in m. C[m,j], M=50176, N=768.
// 64x64 tile, 256 threads, 4x4 micro-tile.
__global__ __launch_bounds__(256) void qkv_gemm(const float* __restrict__ x,
                                                const float* __restrict__ wq,
                                                const float* __restrict__ bq,
                                                float* __restrict__ qkv) {
    __shared__ float As[16][64];   // [k][m]
    __shared__ float Bs[16][64];   // [k][j]
    const int m0 = blockIdx.x * 64;
    const int j0 = blockIdx.y * 64;
    const int b  = m0 / HWP;
    const int p0 = m0 % HWP;
    const float* xb = x + (size_t)b * DIM * HWP;
    const int tid = threadIdx.x;
    const int tx = tid & 15, ty = tid >> 4;
    float acc[4][4] = {};
    for (int k0 = 0; k0 < DIM; k0 += 16) {
        #pragma unroll
        for (int i = 0; i < 4; ++i) {
            int idx = i * 256 + tid;
            int k = idx >> 6, mm = idx & 63;
            As[k][mm] = xb[(size_t)(k0 + k) * HWP + p0 + mm];
            Bs[k][mm] = wq[(size_t)(k0 + k) * NQKV + j0 + mm];
        }
        __syncthreads();
        #pragma unroll
        for (int kk = 0; kk < 16; ++kk) {
            float a[4], bb[4];
            #pragma unroll
            for (int i = 0; i < 4; ++i) a[i] = As[kk][ty * 4 + i];
            #pragma unroll
            for (int j = 0; j < 4; ++j) bb[j] = Bs[kk][tx * 4 + j];
            #pragma unroll
            for (int i = 0; i < 4; ++i)
                #pragma unroll
                for (int j = 0; j < 4; ++j) acc[i][j] += a[i] * bb[j];
        }
        __syncthreads();
    }
    #pragma unroll
    for (int i = 0; i < 4; ++i) {
        int m = m0 + ty * 4 + i;
        float4 v;
        v.x = acc[i][0] + bq[j0 + tx * 4 + 0];
        v.y = acc[i][1] + bq[j0 + tx * 4 + 1];
        v.z = acc[i][2] + bq[j0 + tx * 4 + 2];
        v.w = acc[i][3] + bq[j0 + tx * 4 + 3];
        *(float4*)&qkv[(size_t)m * NQKV + j0 + tx * 4] = v;
    }
}

// ---------------------------------------------------------------------------
// Kernel B: f_conv[b, g*9+o, p] = sum_c fc_w[o,c] * qkv[b,p, c*32+g] + fc_b[o]
// block = 64 threads = 64 pixels for one (b, g).
__global__ __launch_bounds__(64) void fc_kernel(const float* __restrict__ qkv,
                                                const float* __restrict__ fc_w,
                                                const float* __restrict__ fc_b,
                                                float* __restrict__ fconv) {
    __shared__ float w[9][24];
    __shared__ float bsh[9];
    const int tid = threadIdx.x;
    for (int i = tid; i < 216; i += 64) w[i / 24][i % 24] = fc_w[i];
    if (tid < 9) bsh[tid] = fc_b[tid];
    __syncthreads();
    const int p = blockIdx.x * 64 + tid;
    const int g = blockIdx.y;
    const int b = blockIdx.z;
    const float* row = qkv + ((size_t)b * HWP + p) * NQKV + g;
    float f[24];
    #pragma unroll
    for (int c = 0; c < 24; ++c) f[c] = row[c * 32];
    float* outp = fconv + ((size_t)b * 288 + g * 9) * HWP + p;
    #pragma unroll
    for (int o = 0; o < 9; ++o) {
        float s = bsh[o];
        #pragma unroll
        for (int c = 0; c < 24; ++c) s += w[o][c] * f[c];
        outp[(size_t)o * HWP] = s;
    }
}

// ---------------------------------------------------------------------------
// Kernel C: grouped 3x3 conv (pad 1). group g: out channels [8g,8g+8) from
// f_conv planes [9g, 9g+9). Writes rate2 * conv to d_out (NCHW).
__global__ __launch_bounds__(256) void conv_kernel(const float* __restrict__ fconv,
                                                   const float* __restrict__ dep_w,
                                                   const float* __restrict__ rate2p,
                                                   float* __restrict__ out) {
    __shared__ float tile[9][16][16];
    __shared__ float wsh[8][9][9];   // [c8][o][ky*3+kx]
    const int tid = threadIdx.x;
    const int t = blockIdx.x;               // 16 tiles of 14x14
    const int ty0 = (t >> 2) * 14, tx0 = (t & 3) * 14;
    const int g = blockIdx.y, b = blockIdx.z;
    for (int i = tid; i < 648; i += 256) {
        int c8 = i / 81, rest = i % 81;
        wsh[c8][rest / 9][rest % 9] = dep_w[(size_t)(g * 8 + c8) * 81 + rest];
    }
    const float* fp = fconv + ((size_t)b * 288 + g * 9) * HWP;
    for (int i = tid; i < 9 * 256; i += 256) {
        int o = i >> 8, rr = i & 255;
        int yy = ty0 - 1 + (rr >> 4), xx = tx0 - 1 + (rr & 15);
        float v = 0.f;
        if (yy >= 0 && yy < HH && xx >= 0 && xx < WW)
            v = fp[(size_t)o * HWP + yy * WW + xx];
        tile[o][rr >> 4][rr & 15] = v;
    }
    __syncthreads();
    if (tid < 196) {
        const int ly = tid / 14, lx = tid % 14;
        float acc[8] = {};
        #pragma unroll
        for (int o = 0; o < 9; ++o)
            #pragma unroll
            for (int ky = 0; ky < 3; ++ky)
                #pragma unroll
                for (int kx = 0; kx < 3; ++kx) {
                    float v = tile[o][ly + ky][lx + kx];
                    #pragma unroll
                    for (int c8 = 0; c8 < 8; ++c8)
                        acc[c8] += v * wsh[c8][o][ky * 3 + kx];
                }
        const float r2 = rate2p[0];
        const int y = ty0 + ly, xcol = tx0 + lx;
        #pragma unroll
        for (int c8 = 0; c8 < 8; ++c8)
            out[((size_t)b * DIM + g * 8 + c8) * HWP + y * WW + xcol] = r2 * acc[c8];
    }
}

// ---------------------------------------------------------------------------
// Kernel D: window attention. Block per (window, head).
__global__ __launch_bounds__(256) void attn_kernel(const float* __restrict__ qkv,
                                                   const float* __restrict__ rpb,
                                                   float* __restrict__ obuf) {
    __shared__ float q[49][33], k[49][33], v[49][33];
    __shared__ float S[49][50];
    const int tid = threadIdx.x;
    const int h = blockIdx.y;
    const int win = blockIdx.x;
    const int b = win >> 6, wr = win & 63;
    const int wy = wr >> 3, wx = wr & 7;
    for (int i = tid; i < 49 * 32; i += 256) {
        int n = i >> 5, d = i & 31;
        int py = wy * 7 + n / 7, px = wx * 7 + n % 7;
        size_t base = ((size_t)b * HWP + py * WW + px) * NQKV + h * 32 + d;
        q[n][d] = qkv[base];
        k[n][d] = qkv[base + 256];
        v[n][d] = qkv[base + 512];
    }
    __syncthreads();
    const float scale = 0.17677669529663687f;  // 32^-0.5
    for (int i = tid; i < 49 * 49; i += 256) {
        int n = i / 49, m = i % 49;
        float s = 0.f;
        #pragma unroll
        for (int d = 0; d < 32; ++d) s += q[n][d] * k[m][d];
        int dy = n / 7 - m / 7 + 6, dx = n % 7 - m % 7 + 6;
        S[n][m] = s * scale + rpb[(dy * 13 + dx) * NHEADS + h];
    }
    __syncthreads();
    if (tid < 49) {
        float mx = -1e30f;
        for (int m = 0; m < 49; ++m) mx = fmaxf(mx, S[tid][m]);
        float sum = 0.f;
        for (int m = 0; m < 49; ++m) {
            float e = __expf(S[tid][m] - mx);
            S[tid][m] = e;
            sum += e;
        }
        float inv = 1.0f / sum;
        for (int m = 0; m < 49; ++m) S[tid][m] *= inv;
    }
    __syncthreads();
    for (int i = tid; i < 49 * 32; i += 256) {
        int n = i >> 5, d = i & 31;
        float s = 0.f;
        for (int m = 0; m < 49; ++m) s += S[n][m] * v[m][d];
        int py = wy * 7 + n / 7, px = wx * 7 + n % 7;
        obuf[((size_t)b * HWP + py * WW + px) * DIM + h * 32 + d] = s;
    }
}

// ---------------------------------------------------------------------------
// Kernel E: proj GEMM + combine.  out[b,c,p] += rate1 * (obuf @ proj_w^T + pb)
__global__ __launch_bounds__(256) void proj_gemm(const float* __restrict__ obuf,
                                                 const float* __restrict__ pw,
                                                 const float* __restrict__ pb,
                                                 const float* __restrict__ rate1p,
                                                 float* __restrict__ out) {
    __shared__ float As[16][64];   // [k][m]
    __shared__ float Bs[16][64];   // [k][c]
    __shared__ float Ct[64][65];   // [c_local][m_local]
    const int m0 = blockIdx.x * 64;
    const int c0 = blockIdx.y * 64;
    const int tid = threadIdx.x;
    const int tx = tid & 15, ty = tid >> 4;
    float acc[4][4] = {};
    const int mm = tid >> 2, kq4 = (tid & 3) * 4;
    for (int k0 = 0; k0 < DIM; k0 += 16) {
        float4 a = *(const float4*)&obuf[(size_t)(m0 + mm) * DIM + k0 + kq4];
        As[kq4 + 0][mm] = a.x; As[kq4 + 1][mm] = a.y;
        As[kq4 + 2][mm] = a.z; As[kq4 + 3][mm] = a.w;
        float4 bb = *(const float4*)&pw[(size_t)(c0 + mm) * DIM + k0 + kq4];
        Bs[kq4 + 0][mm] = bb.x; Bs[kq4 + 1][mm] = bb.y;
        Bs[kq4 + 2][mm] = bb.z; Bs[kq4 + 3][mm] = bb.w;
        __syncthreads();
        #pragma unroll
        for (int kk = 0; kk < 16; ++kk) {
            float a_[4], b_[4];
            #pragma unroll
            for (int i = 0; i < 4; ++i) a_[i] = As[kk][ty * 4 + i];
            #pragma unroll
            for (int j = 0; j < 4; ++j) b_[j] = Bs[kk][tx * 4 + j];
            #pragma unroll
            for (int i = 0; i < 4; ++i)
                #pragma unroll
                for (int j = 0; j < 4; ++j) acc[i][j] += a_[i] * b_[j];
        }
        __syncthreads();
    }
    #pragma unroll
    for (int i = 0; i < 4; ++i)
        #pragma unroll
        for (int j = 0; j < 4; ++j)
            Ct[tx * 4 + j][ty * 4 + i] = acc[i][j] + pb[c0 + tx * 4 + j];
    __syncthreads();
    const float r1 = rate1p[0];
    const int b = m0 / HWP, p0 = m0 % HWP;
    float* ob = out + (size_t)b * DIM * HWP + p0;
    for (int i = tid; i < 64 * 64; i += 256) {
        int cl = i >> 6, ml = i & 63;
        float* dst = ob + (size_t)(c0 + cl) * HWP + ml;
        *dst = *dst + r1 * Ct[cl][ml];
    }
}

// ---------------------------------------------------------------------------
extern "C" void kernel_launch(void* const* d_in, const int* in_sizes, int n_in,
                              void* d_out, int out_size, void* d_ws, size_t ws_size,
                              hipStream_t stream) {
    const float* x      = (const float*)d_in[0];
    const float* qkv_w  = (const float*)d_in[1];
    const float* qkv_b  = (const float*)d_in[2];
    const float* fc_w   = (const float*)d_in[3];
    const float* fc_b   = (const float*)d_in[4];
    const float* dep_w  = (const float*)d_in[5];
    const float* proj_w = (const float*)d_in[6];
    const float* proj_b = (const float*)d_in[7];
    const float* rpb    = (const float*)d_in[8];
    const float* rate1  = (const float*)d_in[9];
    const float* rate2  = (const float*)d_in[10];
    float* out = (float*)d_out;

    float* qkv   = (float*)d_ws;
    float* fconv = (float*)((char*)d_ws + QKV_BYTES);
    float* obuf  = fconv;  // reused after conv_kernel consumes fconv

    qkv_gemm<<<dim3(M_TOT / 64, NQKV / 64), 256, 0, stream>>>(x, qkv_w, qkv_b, qkv);
    fc_kernel<<<dim3(HWP / 64, 32, BATCH), 64, 0, stream>>>(qkv, fc_w, fc_b, fconv);
    conv_kernel<<<dim3(16, 32, BATCH), 256, 0, stream>>>(fconv, dep_w, rate2, out);
    attn_kernel<<<dim3(1024, NHEADS), 256, 0, stream>>>(qkv, rpb, obuf);
    proj_gemm<<<dim3(M_TOT / 64, DIM / 64), 256, 0, stream>>>(obuf, proj_w, proj_b, rate1, out);
}

// Round 2
// 677.302 us; speedup vs baseline: 1.6841x; 1.6841x over previous
//
#include <hip/hip_runtime.h>

// Problem constants (B=16, DIM=256, H=W=56, NH=8, HD=32, WS=7)
#define BATCH 16
#define DIM 256
#define HH 56
#define WW 56
#define HWP 3136            // 56*56
#define M_TOT 50176         // BATCH*HWP
#define NQKV 768            // 3*DIM
#define NHEADS 8
#define HDIM 32
#define NWIN 49             // 7*7
#define QKV_BYTES 154140672ull  // M_TOT*NQKV*4

// ---------------------------------------------------------------------------
// Kernel A: qkv = x^T @ qkv_w + qkv_b
// x is (B, C=256, HW) so A^T[k, m] is contiguous in m. C[m,j], M=50176, N=768.
// 64x64 tile, 256 threads, 4x4 micro-tile.
__global__ __launch_bounds__(256) void qkv_gemm(const float* __restrict__ x,
                                                const float* __restrict__ wq,
                                                const float* __restrict__ bq,
                                                float* __restrict__ qkv) {
    __shared__ float As[16][64];   // [k][m]
    __shared__ float Bs[16][64];   // [k][j]
    const int m0 = blockIdx.x * 64;
    const int j0 = blockIdx.y * 64;
    const int b  = m0 / HWP;
    const int p0 = m0 % HWP;
    const float* xb = x + (size_t)b * DIM * HWP;
    const int tid = threadIdx.x;
    const int tx = tid & 15, ty = tid >> 4;
    float acc[4][4] = {};
    for (int k0 = 0; k0 < DIM; k0 += 16) {
        #pragma unroll
        for (int i = 0; i < 4; ++i) {
            int idx = i * 256 + tid;
            int k = idx >> 6, mm = idx & 63;
            As[k][mm] = xb[(size_t)(k0 + k) * HWP + p0 + mm];
            Bs[k][mm] = wq[(size_t)(k0 + k) * NQKV + j0 + mm];
        }
        __syncthreads();
        #pragma unroll
        for (int kk = 0; kk < 16; ++kk) {
            float a[4], bb[4];
            #pragma unroll
            for (int i = 0; i < 4; ++i) a[i] = As[kk][ty * 4 + i];
            #pragma unroll
            for (int j = 0; j < 4; ++j) bb[j] = Bs[kk][tx * 4 + j];
            #pragma unroll
            for (int i = 0; i < 4; ++i)
                #pragma unroll
                for (int j = 0; j < 4; ++j) acc[i][j] += a[i] * bb[j];
        }
        __syncthreads();
    }
    #pragma unroll
    for (int i = 0; i < 4; ++i) {
        int m = m0 + ty * 4 + i;
        float4 v;
        v.x = acc[i][0] + bq[j0 + tx * 4 + 0];
        v.y = acc[i][1] + bq[j0 + tx * 4 + 1];
        v.z = acc[i][2] + bq[j0 + tx * 4 + 2];
        v.w = acc[i][3] + bq[j0 + tx * 4 + 3];
        *(float4*)&qkv[(size_t)m * NQKV + j0 + tx * 4] = v;
    }
}

// ---------------------------------------------------------------------------
// Kernel B (v2, coalesced): f_conv[b, g*9+o, p] = sum_c fc_w[o,c]*qkv[b,p,c*32+g] + fc_b[o]
// Block = 256 threads, 16 consecutive pixels, all 32 g. LDS-staged both ways.
__global__ __launch_bounds__(256) void fc_kernel(const float* __restrict__ qkv,
                                                 const float* __restrict__ fc_w,
                                                 const float* __restrict__ fc_b,
                                                 float* __restrict__ fconv) {
    __shared__ float f[16 * 768];     // 48 KB, linear copies of 16 qkv rows
    __shared__ float ob[16][289];     // padded output staging
    __shared__ float w[9][24];
    __shared__ float bsh[9];
    const int tid = threadIdx.x;
    if (tid < 216) w[tid / 24][tid % 24] = fc_w[tid];
    if (tid < 9) bsh[tid] = fc_b[tid];
    const int p0 = blockIdx.x * 16;
    const int b  = blockIdx.y;
    // contiguous 12288-float span: rows p0..p0+15 of image b
    const float4* src = (const float4*)(qkv + ((size_t)b * HWP + p0) * NQKV);
    float4* dstf = (float4*)f;
    #pragma unroll
    for (int i = 0; i < 12; ++i) dstf[tid + i * 256] = src[tid + i * 256];
    __syncthreads();
    #pragma unroll
    for (int it = 0; it < 2; ++it) {
        const int item = tid + it * 256;
        const int pp = item >> 5, g = item & 31;
        const float* fr = f + pp * 768 + g;
        float acc[9];
        #pragma unroll
        for (int o = 0; o < 9; ++o) acc[o] = bsh[o];
        #pragma unroll
        for (int c = 0; c < 24; ++c) {
            float v = fr[c * 32];
            #pragma unroll
            for (int o = 0; o < 9; ++o) acc[o] += w[o][c] * v;
        }
        #pragma unroll
        for (int o = 0; o < 9; ++o) ob[pp][g * 9 + o] = acc[o];
    }
    __syncthreads();
    float* og = fconv + (size_t)b * 288 * HWP + p0;
    for (int i = tid; i < 288 * 16; i += 256) {
        int ch = i >> 4, pp = i & 15;
        og[(size_t)ch * HWP + pp] = ob[pp][ch];
    }
}

// ---------------------------------------------------------------------------
// Kernel C: grouped 3x3 conv (pad 1). group g: out channels [8g,8g+8) from
// f_conv planes [9g, 9g+9). Writes rate2 * conv to d_out (NCHW).
__global__ __launch_bounds__(256) void conv_kernel(const float* __restrict__ fconv,
                                                   const float* __restrict__ dep_w,
                                                   const float* __restrict__ rate2p,
                                                   float* __restrict__ out) {
    __shared__ float tile[9][16][16];
    __shared__ float wsh[8][9][9];   // [c8][o][ky*3+kx]
    const int tid = threadIdx.x;
    const int t = blockIdx.x;               // 16 tiles of 14x14
    const int ty0 = (t >> 2) * 14, tx0 = (t & 3) * 14;
    const int g = blockIdx.y, b = blockIdx.z;
    for (int i = tid; i < 648; i += 256) {
        int c8 = i / 81, rest = i % 81;
        wsh[c8][rest / 9][rest % 9] = dep_w[(size_t)(g * 8 + c8) * 81 + rest];
    }
    const float* fp = fconv + ((size_t)b * 288 + g * 9) * HWP;
    for (int i = tid; i < 9 * 256; i += 256) {
        int o = i >> 8, rr = i & 255;
        int yy = ty0 - 1 + (rr >> 4), xx = tx0 - 1 + (rr & 15);
        float v = 0.f;
        if (yy >= 0 && yy < HH && xx >= 0 && xx < WW)
            v = fp[(size_t)o * HWP + yy * WW + xx];
        tile[o][rr >> 4][rr & 15] = v;
    }
    __syncthreads();
    if (tid < 196) {
        const int ly = tid / 14, lx = tid % 14;
        float acc[8] = {};
        #pragma unroll
        for (int o = 0; o < 9; ++o)
            #pragma unroll
            for (int ky = 0; ky < 3; ++ky)
                #pragma unroll
                for (int kx = 0; kx < 3; ++kx) {
                    float v = tile[o][ly + ky][lx + kx];
                    #pragma unroll
                    for (int c8 = 0; c8 < 8; ++c8)
                        acc[c8] += v * wsh[c8][o][ky * 3 + kx];
                }
        const float r2 = rate2p[0];
        const int y = ty0 + ly, xcol = tx0 + lx;
        #pragma unroll
        for (int c8 = 0; c8 < 8; ++c8)
            out[((size_t)b * DIM + g * 8 + c8) * HWP + y * WW + xcol] = r2 * acc[c8];
    }
}

// ---------------------------------------------------------------------------
// Kernel D: window attention. Block per (window, head).
__global__ __launch_bounds__(256) void attn_kernel(const float* __restrict__ qkv,
                                                   const float* __restrict__ rpb,
                                                   float* __restrict__ obuf) {
    __shared__ float q[49][33], k[49][33], v[49][33];
    __shared__ float S[49][50];
    const int tid = threadIdx.x;
    const int h = blockIdx.y;
    const int win = blockIdx.x;
    const int b = win >> 6, wr = win & 63;
    const int wy = wr >> 3, wx = wr & 7;
    for (int i = tid; i < 49 * 32; i += 256) {
        int n = i >> 5, d = i & 31;
        int py = wy * 7 + n / 7, px = wx * 7 + n % 7;
        size_t base = ((size_t)b * HWP + py * WW + px) * NQKV + h * 32 + d;
        q[n][d] = qkv[base];
        k[n][d] = qkv[base + 256];
        v[n][d] = qkv[base + 512];
    }
    __syncthreads();
    const float scale = 0.17677669529663687f;  // 32^-0.5
    for (int i = tid; i < 49 * 49; i += 256) {
        int n = i / 49, m = i % 49;
        float s = 0.f;
        #pragma unroll
        for (int d = 0; d < 32; ++d) s += q[n][d] * k[m][d];
        int dy = n / 7 - m / 7 + 6, dx = n % 7 - m % 7 + 6;
        S[n][m] = s * scale + rpb[(dy * 13 + dx) * NHEADS + h];
    }
    __syncthreads();
    if (tid < 49) {
        float mx = -1e30f;
        for (int m = 0; m < 49; ++m) mx = fmaxf(mx, S[tid][m]);
        float sum = 0.f;
        for (int m = 0; m < 49; ++m) {
            float e = __expf(S[tid][m] - mx);
            S[tid][m] = e;
            sum += e;
        }
        float inv = 1.0f / sum;
        for (int m = 0; m < 49; ++m) S[tid][m] *= inv;
    }
    __syncthreads();
    for (int i = tid; i < 49 * 32; i += 256) {
        int n = i >> 5, d = i & 31;
        float s = 0.f;
        for (int m = 0; m < 49; ++m) s += S[n][m] * v[m][d];
        int py = wy * 7 + n / 7, px = wx * 7 + n % 7;
        obuf[((size_t)b * HWP + py * WW + px) * DIM + h * 32 + d] = s;
    }
}

// ---------------------------------------------------------------------------
// Kernel E: proj GEMM + combine.  out[b,c,p] += rate1 * (obuf @ proj_w^T + pb)
__global__ __launch_bounds__(256) void proj_gemm(const float* __restrict__ obuf,
                                                 const float* __restrict__ pw,
                                                 const float* __restrict__ pb,
                                                 const float* __restrict__ rate1p,
                                                 float* __restrict__ out) {
    __shared__ float As[16][64];   // [k][m]
    __shared__ float Bs[16][64];   // [k][c]
    __shared__ float Ct[64][65];   // [c_local][m_local]
    const int m0 = blockIdx.x * 64;
    const int c0 = blockIdx.y * 64;
    const int tid = threadIdx.x;
    const int tx = tid & 15, ty = tid >> 4;
    float acc[4][4] = {};
    const int mm = tid >> 2, kq4 = (tid & 3) * 4;
    for (int k0 = 0; k0 < DIM; k0 += 16) {
        float4 a = *(const float4*)&obuf[(size_t)(m0 + mm) * DIM + k0 + kq4];
        As[kq4 + 0][mm] = a.x; As[kq4 + 1][mm] = a.y;
        As[kq4 + 2][mm] = a.z; As[kq4 + 3][mm] = a.w;
        float4 bb = *(const float4*)&pw[(size_t)(c0 + mm) * DIM + k0 + kq4];
        Bs[kq4 + 0][mm] = bb.x; Bs[kq4 + 1][mm] = bb.y;
        Bs[kq4 + 2][mm] = bb.z; Bs[kq4 + 3][mm] = bb.w;
        __syncthreads();
        #pragma unroll
        for (int kk = 0; kk < 16; ++kk) {
            float a_[4], b_[4];
            #pragma unroll
            for (int i = 0; i < 4; ++i) a_[i] = As[kk][ty * 4 + i];
            #pragma unroll
            for (int j = 0; j < 4; ++j) b_[j] = Bs[kk][tx * 4 + j];
            #pragma unroll
            for (int i = 0; i < 4; ++i)
                #pragma unroll
                for (int j = 0; j < 4; ++j) acc[i][j] += a_[i] * b_[j];
        }
        __syncthreads();
    }
    #pragma unroll
    for (int i = 0; i < 4; ++i)
        #pragma unroll
        for (int j = 0; j < 4; ++j)
            Ct[tx * 4 + j][ty * 4 + i] = acc[i][j] + pb[c0 + tx * 4 + j];
    __syncthreads();
    const float r1 = rate1p[0];
    const int b = m0 / HWP, p0 = m0 % HWP;
    float* ob = out + (size_t)b * DIM * HWP + p0;
    for (int i = tid; i < 64 * 64; i += 256) {
        int cl = i >> 6, ml = i & 63;
        float* dst = ob + (size_t)(c0 + cl) * HWP + ml;
        *dst = *dst + r1 * Ct[cl][ml];
    }
}

// ---------------------------------------------------------------------------
extern "C" void kernel_launch(void* const* d_in, const int* in_sizes, int n_in,
                              void* d_out, int out_size, void* d_ws, size_t ws_size,
                              hipStream_t stream) {
    const float* x      = (const float*)d_in[0];
    const float* qkv_w  = (const float*)d_in[1];
    const float* qkv_b  = (const float*)d_in[2];
    const float* fc_w   = (const float*)d_in[3];
    const float* fc_b   = (const float*)d_in[4];
    const float* dep_w  = (const float*)d_in[5];
    const float* proj_w = (const float*)d_in[6];
    const float* proj_b = (const float*)d_in[7];
    const float* rpb    = (const float*)d_in[8];
    const float* rate1  = (const float*)d_in[9];
    const float* rate2  = (const float*)d_in[10];
    float* out = (float*)d_out;

    float* qkv   = (float*)d_ws;
    float* fconv = (float*)((char*)d_ws + QKV_BYTES);
    float* obuf  = fconv;  // reused after conv_kernel consumes fconv

    qkv_gemm<<<dim3(M_TOT / 64, NQKV / 64), 256, 0, stream>>>(x, qkv_w, qkv_b, qkv);
    fc_kernel<<<dim3(HWP / 16, BATCH), 256, 0, stream>>>(qkv, fc_w, fc_b, fconv);
    conv_kernel<<<dim3(16, 32, BATCH), 256, 0, stream>>>(fconv, dep_w, rate2, out);
    attn_kernel<<<dim3(1024, NHEADS), 256, 0, stream>>>(qkv, rpb, obuf);
    proj_gemm<<<dim3(M_TOT / 64, DIM / 64), 256, 0, stream>>>(obuf, proj_w, proj_b, rate1, out);
}

// Round 3
// 471.767 us; speedup vs baseline: 2.4178x; 1.4357x over previous
//
#include <hip/hip_runtime.h>

// Problem constants (B=16, DIM=256, H=W=56, NH=8, HD=32, WS=7)
#define BATCH 16
#define DIM 256
#define HH 56
#define WW 56
#define HWP 3136            // 56*56
#define M_TOT 50176         // BATCH*HWP
#define NQKV 768            // 3*DIM
#define NHEADS 8
#define HDIM 32
#define NWIN 49             // 7*7
#define QKV_BYTES 154140672ull  // M_TOT*NQKV*4

typedef float f32x4 __attribute__((ext_vector_type(4)));
typedef short short8 __attribute__((ext_vector_type(8)));

__device__ __forceinline__ short f2bf(float f) {
    unsigned u = __float_as_uint(f);
    u += 0x7fffu + ((u >> 16) & 1u);   // RNE
    return (short)(u >> 16);
}

// ---------------------------------------------------------------------------
// Kernel A (v2, MFMA): qkv[m][j] = sum_k x^T[k][m] * wq[k][j] + bq[j]
// 128x128 tile, BK=64, 4 waves (64x64 quadrant each, 4x4 frags of 16x16x32).
// LDS layout: [row][64 bf16] with kgrp ^= (row&7) 16B-slot swizzle (8-slot
// b128 floor on both ds_write and frag ds_read).
__global__ __launch_bounds__(256) void qkv_gemm(const float* __restrict__ x,
                                                const float* __restrict__ wq,
                                                const float* __restrict__ bq,
                                                float* __restrict__ qkv) {
    __shared__ short A_lds[128 * 64];
    __shared__ short B_lds[128 * 64];
    // XCD-aware swizzle: grid = 2352 = 8 * 294, consecutive wg per XCD
    const int bidx = blockIdx.x;
    const int wg = (bidx & 7) * 294 + (bidx >> 3);
    const int jt = wg % 6, mt = wg / 6;
    const int m0 = mt * 128, j0 = jt * 128;

    const int tid = threadIdx.x;
    const int lane = tid & 63;
    const int wave = tid >> 6;
    const int wr = wave >> 1, wc = wave & 1;

    // staging coords: thread -> (row 0..127, k-half 0/1)
    const int srow = tid & 127;
    const int kh = tid >> 7;
    const int gm = m0 + srow;
    const int sb = gm / HWP, sp = gm % HWP;
    const float* aptr = x + ((size_t)sb * DIM + kh * 32) * HWP + sp;
    const float* bptr = wq + (size_t)(kh * 32) * NQKV + j0 + srow;

    f32x4 acc[4][4];
    #pragma unroll
    for (int i = 0; i < 4; ++i)
        #pragma unroll
        for (int j = 0; j < 4; ++j) acc[i][j] = (f32x4){0.f, 0.f, 0.f, 0.f};

    const int r = lane & 15, q = lane >> 4;
    for (int k0 = 0; k0 < DIM; k0 += 64) {
        __syncthreads();
        const float* ap = aptr + (size_t)k0 * HWP;
        #pragma unroll
        for (int g = 0; g < 4; ++g) {
            short8 s;
            #pragma unroll
            for (int i = 0; i < 8; ++i) s[i] = f2bf(ap[(size_t)(g * 8 + i) * HWP]);
            *(short8*)&A_lds[srow * 64 + 8 * ((kh * 4 + g) ^ (srow & 7))] = s;
        }
        const float* bp = bptr + (size_t)k0 * NQKV;
        #pragma unroll
        for (int g = 0; g < 4; ++g) {
            short8 s;
            #pragma unroll
            for (int i = 0; i < 8; ++i) s[i] = f2bf(bp[(size_t)(g * 8 + i) * NQKV]);
            *(short8*)&B_lds[srow * 64 + 8 * ((kh * 4 + g) ^ (srow & 7))] = s;
        }
        __syncthreads();
        #pragma unroll
        for (int ks = 0; ks < 2; ++ks) {
            short8 af[4], bfr[4];
            #pragma unroll
            for (int f = 0; f < 4; ++f) {
                int mrow = wr * 64 + f * 16 + r;
                af[f] = *(const short8*)&A_lds[mrow * 64 + 8 * ((ks * 4 + q) ^ (mrow & 7))];
                int nrow = wc * 64 + f * 16 + r;
                bfr[f] = *(const short8*)&B_lds[nrow * 64 + 8 * ((ks * 4 + q) ^ (nrow & 7))];
            }
            #pragma unroll
            for (int fm = 0; fm < 4; ++fm)
                #pragma unroll
                for (int fj = 0; fj < 4; ++fj)
                    acc[fm][fj] = __builtin_amdgcn_mfma_f32_16x16x32_bf16(
                        af[fm], bfr[fj], acc[fm][fj], 0, 0, 0);
        }
    }
    // epilogue: C/D layout col = lane&15, row = (lane>>4)*4 + reg
    #pragma unroll
    for (int fm = 0; fm < 4; ++fm) {
        const int mbase = m0 + wr * 64 + fm * 16 + q * 4;
        #pragma unroll
        for (int fj = 0; fj < 4; ++fj) {
            const int j = j0 + wc * 64 + fj * 16 + r;
            const float bias = bq[j];
            float* op = qkv + (size_t)mbase * NQKV + j;
            #pragma unroll
            for (int rg = 0; rg < 4; ++rg)
                op[(size_t)rg * NQKV] = acc[fm][fj][rg] + bias;
        }
    }
}

// ---------------------------------------------------------------------------
// Kernel B (coalesced): f_conv[b, g*9+o, p] = sum_c fc_w[o,c]*qkv[b,p,c*32+g] + fc_b[o]
__global__ __launch_bounds__(256) void fc_kernel(const float* __restrict__ qkv,
                                                 const float* __restrict__ fc_w,
                                                 const float* __restrict__ fc_b,
                                                 float* __restrict__ fconv) {
    __shared__ float f[16 * 768];     // 48 KB, linear copies of 16 qkv rows
    __shared__ float ob[16][289];     // padded output staging
    __shared__ float w[9][24];
    __shared__ float bsh[9];
    const int tid = threadIdx.x;
    if (tid < 216) w[tid / 24][tid % 24] = fc_w[tid];
    if (tid < 9) bsh[tid] = fc_b[tid];
    const int p0 = blockIdx.x * 16;
    const int b  = blockIdx.y;
    const float4* src = (const float4*)(qkv + ((size_t)b * HWP + p0) * NQKV);
    float4* dstf = (float4*)f;
    #pragma unroll
    for (int i = 0; i < 12; ++i) dstf[tid + i * 256] = src[tid + i * 256];
    __syncthreads();
    #pragma unroll
    for (int it = 0; it < 2; ++it) {
        const int item = tid + it * 256;
        const int pp = item >> 5, g = item & 31;
        const float* fr = f + pp * 768 + g;
        float acc[9];
        #pragma unroll
        for (int o = 0; o < 9; ++o) acc[o] = bsh[o];
        #pragma unroll
        for (int c = 0; c < 24; ++c) {
            float v = fr[c * 32];
            #pragma unroll
            for (int o = 0; o < 9; ++o) acc[o] += w[o][c] * v;
        }
        #pragma unroll
        for (int o = 0; o < 9; ++o) ob[pp][g * 9 + o] = acc[o];
    }
    __syncthreads();
    float* og = fconv + (size_t)b * 288 * HWP + p0;
    for (int i = tid; i < 288 * 16; i += 256) {
        int ch = i >> 4, pp = i & 15;
        og[(size_t)ch * HWP + pp] = ob[pp][ch];
    }
}

// ---------------------------------------------------------------------------
// Kernel C: grouped 3x3 conv (pad 1). Writes rate2 * conv to d_out (NCHW).
__global__ __launch_bounds__(256) void conv_kernel(const float* __restrict__ fconv,
                                                   const float* __restrict__ dep_w,
                                                   const float* __restrict__ rate2p,
                                                   float* __restrict__ out) {
    __shared__ float tile[9][16][16];
    __shared__ float wsh[8][9][9];   // [c8][o][ky*3+kx]
    const int tid = threadIdx.x;
    const int t = blockIdx.x;               // 16 tiles of 14x14
    const int ty0 = (t >> 2) * 14, tx0 = (t & 3) * 14;
    const int g = blockIdx.y, b = blockIdx.z;
    for (int i = tid; i < 648; i += 256) {
        int c8 = i / 81, rest = i % 81;
        wsh[c8][rest / 9][rest % 9] = dep_w[(size_t)(g * 8 + c8) * 81 + rest];
    }
    const float* fp = fconv + ((size_t)b * 288 + g * 9) * HWP;
    for (int i = tid; i < 9 * 256; i += 256) {
        int o = i >> 8, rr = i & 255;
        int yy = ty0 - 1 + (rr >> 4), xx = tx0 - 1 + (rr & 15);
        float v = 0.f;
        if (yy >= 0 && yy < HH && xx >= 0 && xx < WW)
            v = fp[(size_t)o * HWP + yy * WW + xx];
        tile[o][rr >> 4][rr & 15] = v;
    }
    __syncthreads();
    if (tid < 196) {
        const int ly = tid / 14, lx = tid % 14;
        float acc[8] = {};
        #pragma unroll
        for (int o = 0; o < 9; ++o)
            #pragma unroll
            for (int ky = 0; ky < 3; ++ky)
                #pragma unroll
                for (int kx = 0; kx < 3; ++kx) {
                    float v = tile[o][ly + ky][lx + kx];
                    #pragma unroll
                    for (int c8 = 0; c8 < 8; ++c8)
                        acc[c8] += v * wsh[c8][o][ky * 3 + kx];
                }
        const float r2 = rate2p[0];
        const int y = ty0 + ly, xcol = tx0 + lx;
        #pragma unroll
        for (int c8 = 0; c8 < 8; ++c8)
            out[((size_t)b * DIM + g * 8 + c8) * HWP + y * WW + xcol] = r2 * acc[c8];
    }
}

// ---------------------------------------------------------------------------
// Kernel D: window attention. Block per (window, head).
__global__ __launch_bounds__(256) void attn_kernel(const float* __restrict__ qkv,
                                                   const float* __restrict__ rpb,
                                                   float* __restrict__ obuf) {
    __shared__ float q[49][33], k[49][33], v[49][33];
    __shared__ float S[49][50];
    const int tid = threadIdx.x;
    const int h = blockIdx.y;
    const int win = blockIdx.x;
    const int b = win >> 6, wr = win & 63;
    const int wy = wr >> 3, wx = wr & 7;
    for (int i = tid; i < 49 * 32; i += 256) {
        int n = i >> 5, d = i & 31;
        int py = wy * 7 + n / 7, px = wx * 7 + n % 7;
        size_t base = ((size_t)b * HWP + py * WW + px) * NQKV + h * 32 + d;
        q[n][d] = qkv[base];
        k[n][d] = qkv[base + 256];
        v[n][d] = qkv[base + 512];
    }
    __syncthreads();
    const float scale = 0.17677669529663687f;  // 32^-0.5
    for (int i = tid; i < 49 * 49; i += 256) {
        int n = i / 49, m = i % 49;
        float s = 0.f;
        #pragma unroll
        for (int d = 0; d < 32; ++d) s += q[n][d] * k[m][d];
        int dy = n / 7 - m / 7 + 6, dx = n % 7 - m % 7 + 6;
        S[n][m] = s * scale + rpb[(dy * 13 + dx) * NHEADS + h];
    }
    __syncthreads();
    if (tid < 49) {
        float mx = -1e30f;
        for (int m = 0; m < 49; ++m) mx = fmaxf(mx, S[tid][m]);
        float sum = 0.f;
        for (int m = 0; m < 49; ++m) {
            float e = __expf(S[tid][m] - mx);
            S[tid][m] = e;
            sum += e;
        }
        float inv = 1.0f / sum;
        for (int m = 0; m < 49; ++m) S[tid][m] *= inv;
    }
    __syncthreads();
    for (int i = tid; i < 49 * 32; i += 256) {
        int n = i >> 5, d = i & 31;
        float s = 0.f;
        for (int m = 0; m < 49; ++m) s += S[n][m] * v[m][d];
        int py = wy * 7 + n / 7, px = wx * 7 + n % 7;
        obuf[((size_t)b * HWP + py * WW + px) * DIM + h * 32 + d] = s;
    }
}

// ---------------------------------------------------------------------------
// Kernel E: proj GEMM + combine.  out[b,c,p] += rate1 * (obuf @ proj_w^T + pb)
__global__ __launch_bounds__(256) void proj_gemm(const float* __restrict__ obuf,
                                                 const float* __restrict__ pw,
                                                 const float* __restrict__ pb,
                                                 const float* __restrict__ rate1p,
                                                 float* __restrict__ out) {
    __shared__ float As[16][64];   // [k][m]
    __shared__ float Bs[16][64];   // [k][c]
    __shared__ float Ct[64][65];   // [c_local][m_local]
    const int m0 = blockIdx.x * 64;
    const int c0 = blockIdx.y * 64;
    const int tid = threadIdx.x;
    const int tx = tid & 15, ty = tid >> 4;
    float acc[4][4] = {};
    const int mm = tid >> 2, kq4 = (tid & 3) * 4;
    for (int k0 = 0; k0 < DIM; k0 += 16) {
        float4 a = *(const float4*)&obuf[(size_t)(m0 + mm) * DIM + k0 + kq4];
        As[kq4 + 0][mm] = a.x; As[kq4 + 1][mm] = a.y;
        As[kq4 + 2][mm] = a.z; As[kq4 + 3][mm] = a.w;
        float4 bb = *(const float4*)&pw[(size_t)(c0 + mm) * DIM + k0 + kq4];
        Bs[kq4 + 0][mm] = bb.x; Bs[kq4 + 1][mm] = bb.y;
        Bs[kq4 + 2][mm] = bb.z; Bs[kq4 + 3][mm] = bb.w;
        __syncthreads();
        #pragma unroll
        for (int kk = 0; kk < 16; ++kk) {
            float a_[4], b_[4];
            #pragma unroll
            for (int i = 0; i < 4; ++i) a_[i] = As[kk][ty * 4 + i];
            #pragma unroll
            for (int j = 0; j < 4; ++j) b_[j] = Bs[kk][tx * 4 + j];
            #pragma unroll
            for (int i = 0; i < 4; ++i)
                #pragma unroll
                for (int j = 0; j < 4; ++j) acc[i][j] += a_[i] * b_[j];
        }
        __syncthreads();
    }
    #pragma unroll
    for (int i = 0; i < 4; ++i)
        #pragma unroll
        for (int j = 0; j < 4; ++j)
            Ct[tx * 4 + j][ty * 4 + i] = acc[i][j] + pb[c0 + tx * 4 + j];
    __syncthreads();
    const float r1 = rate1p[0];
    const int b = m0 / HWP, p0 = m0 % HWP;
    float* ob = out + (size_t)b * DIM * HWP + p0;
    for (int i = tid; i < 64 * 64; i += 256) {
        int cl = i >> 6, ml = i & 63;
        float* dst = ob + (size_t)(c0 + cl) * HWP + ml;
        *dst = *dst + r1 * Ct[cl][ml];
    }
}

// ---------------------------------------------------------------------------
extern "C" void kernel_launch(void* const* d_in, const int* in_sizes, int n_in,
                              void* d_out, int out_size, void* d_ws, size_t ws_size,
                              hipStream_t stream) {
    const float* x      = (const float*)d_in[0];
    const float* qkv_w  = (const float*)d_in[1];
    const float* qkv_b  = (const float*)d_in[2];
    const float* fc_w   = (const float*)d_in[3];
    const float* fc_b   = (const float*)d_in[4];
    const float* dep_w  = (const float*)d_in[5];
    const float* proj_w = (const float*)d_in[6];
    const float* proj_b = (const float*)d_in[7];
    const float* rpb    = (const float*)d_in[8];
    const float* rate1  = (const float*)d_in[9];
    const float* rate2  = (const float*)d_in[10];
    float* out = (float*)d_out;

    float* qkv   = (float*)d_ws;
    float* fconv = (float*)((char*)d_ws + QKV_BYTES);
    float* obuf  = fconv;  // reused after conv_kernel consumes fconv

    qkv_gemm<<<dim3(2352), 256, 0, stream>>>(x, qkv_w, qkv_b, qkv);
    fc_kernel<<<dim3(HWP / 16, BATCH), 256, 0, stream>>>(qkv, fc_w, fc_b, fconv);
    conv_kernel<<<dim3(16, 32, BATCH), 256, 0, stream>>>(fconv, dep_w, rate2, out);
    attn_kernel<<<dim3(1024, NHEADS), 256, 0, stream>>>(qkv, rpb, obuf);
    proj_gemm<<<dim3(M_TOT / 64, DIM / 64), 256, 0, stream>>>(obuf, proj_w, proj_b, rate1, out);
}

// Round 4
// 396.042 us; speedup vs baseline: 2.8801x; 1.1912x over previous
//
#include <hip/hip_runtime.h>

// Problem constants (B=16, DIM=256, H=W=56, NH=8, HD=32, WS=7)
#define BATCH 16
#define DIM 256
#define HH 56
#define WW 56
#define HWP 3136            // 56*56
#define M_TOT 50176         // BATCH*HWP
#define NQKV 768            // 3*DIM
#define NHEADS 8
#define HDIM 32
#define NWIN 49             // 7*7
#define QKV_BYTES 154140672ull  // M_TOT*NQKV*4

typedef float f32x4 __attribute__((ext_vector_type(4)));
typedef short short8 __attribute__((ext_vector_type(8)));

__device__ __forceinline__ short f2bf(float f) {
    unsigned u = __float_as_uint(f);
    u += 0x7fffu + ((u >> 16) & 1u);   // RNE
    return (short)(u >> 16);
}
__device__ __forceinline__ unsigned pack2bf(float lo, float hi) {
    unsigned ul = __float_as_uint(lo); ul += 0x7fffu + ((ul >> 16) & 1u);
    unsigned uh = __float_as_uint(hi); uh += 0x7fffu + ((uh >> 16) & 1u);
    return (ul >> 16) | (uh & 0xffff0000u);
}
__device__ __forceinline__ int div7(int n) { return (n * 9363) >> 16; }  // exact for 0..63

// ---------------------------------------------------------------------------
// Kernel A (MFMA): qkv[m][j] = sum_k x^T[k][m] * wq[k][j] + bq[j]
__global__ __launch_bounds__(256) void qkv_gemm(const float* __restrict__ x,
                                                const float* __restrict__ wq,
                                                const float* __restrict__ bq,
                                                float* __restrict__ qkv) {
    __shared__ short A_lds[128 * 64];
    __shared__ short B_lds[128 * 64];
    const int bidx = blockIdx.x;
    const int wg = (bidx & 7) * 294 + (bidx >> 3);
    const int jt = wg % 6, mt = wg / 6;
    const int m0 = mt * 128, j0 = jt * 128;

    const int tid = threadIdx.x;
    const int lane = tid & 63;
    const int wave = tid >> 6;
    const int wr = wave >> 1, wc = wave & 1;

    const int srow = tid & 127;
    const int kh = tid >> 7;
    const int gm = m0 + srow;
    const int sb = gm / HWP, sp = gm % HWP;
    const float* aptr = x + ((size_t)sb * DIM + kh * 32) * HWP + sp;
    const float* bptr = wq + (size_t)(kh * 32) * NQKV + j0 + srow;

    f32x4 acc[4][4];
    #pragma unroll
    for (int i = 0; i < 4; ++i)
        #pragma unroll
        for (int j = 0; j < 4; ++j) acc[i][j] = (f32x4){0.f, 0.f, 0.f, 0.f};

    const int r = lane & 15, q = lane >> 4;
    for (int k0 = 0; k0 < DIM; k0 += 64) {
        __syncthreads();
        const float* ap = aptr + (size_t)k0 * HWP;
        #pragma unroll
        for (int g = 0; g < 4; ++g) {
            short8 s;
            #pragma unroll
            for (int i = 0; i < 8; ++i) s[i] = f2bf(ap[(size_t)(g * 8 + i) * HWP]);
            *(short8*)&A_lds[srow * 64 + 8 * ((kh * 4 + g) ^ (srow & 7))] = s;
        }
        const float* bp = bptr + (size_t)k0 * NQKV;
        #pragma unroll
        for (int g = 0; g < 4; ++g) {
            short8 s;
            #pragma unroll
            for (int i = 0; i < 8; ++i) s[i] = f2bf(bp[(size_t)(g * 8 + i) * NQKV]);
            *(short8*)&B_lds[srow * 64 + 8 * ((kh * 4 + g) ^ (srow & 7))] = s;
        }
        __syncthreads();
        #pragma unroll
        for (int ks = 0; ks < 2; ++ks) {
            short8 af[4], bfr[4];
            #pragma unroll
            for (int f = 0; f < 4; ++f) {
                int mrow = wr * 64 + f * 16 + r;
                af[f] = *(const short8*)&A_lds[mrow * 64 + 8 * ((ks * 4 + q) ^ (mrow & 7))];
                int nrow = wc * 64 + f * 16 + r;
                bfr[f] = *(const short8*)&B_lds[nrow * 64 + 8 * ((ks * 4 + q) ^ (nrow & 7))];
            }
            #pragma unroll
            for (int fm = 0; fm < 4; ++fm)
                #pragma unroll
                for (int fj = 0; fj < 4; ++fj)
                    acc[fm][fj] = __builtin_amdgcn_mfma_f32_16x16x32_bf16(
                        af[fm], bfr[fj], acc[fm][fj], 0, 0, 0);
        }
    }
    #pragma unroll
    for (int fm = 0; fm < 4; ++fm) {
        const int mbase = m0 + wr * 64 + fm * 16 + q * 4;
        #pragma unroll
        for (int fj = 0; fj < 4; ++fj) {
            const int j = j0 + wc * 64 + fj * 16 + r;
            const float bias = bq[j];
            float* op = qkv + (size_t)mbase * NQKV + j;
            #pragma unroll
            for (int rg = 0; rg < 4; ++rg)
                op[(size_t)rg * NQKV] = acc[fm][fj][rg] + bias;
        }
    }
}

// ---------------------------------------------------------------------------
// Kernel B: f_conv[b, g*9+o, p] = sum_c fc_w[o,c]*qkv[b,p,c*32+g] + fc_b[o]
__global__ __launch_bounds__(256) void fc_kernel(const float* __restrict__ qkv,
                                                 const float* __restrict__ fc_w,
                                                 const float* __restrict__ fc_b,
                                                 float* __restrict__ fconv) {
    __shared__ float f[16 * 768];
    __shared__ float ob[16][289];
    __shared__ float w[9][24];
    __shared__ float bsh[9];
    const int tid = threadIdx.x;
    if (tid < 216) w[tid / 24][tid % 24] = fc_w[tid];
    if (tid < 9) bsh[tid] = fc_b[tid];
    const int p0 = blockIdx.x * 16;
    const int b  = blockIdx.y;
    const float4* src = (const float4*)(qkv + ((size_t)b * HWP + p0) * NQKV);
    float4* dstf = (float4*)f;
    #pragma unroll
    for (int i = 0; i < 12; ++i) dstf[tid + i * 256] = src[tid + i * 256];
    __syncthreads();
    #pragma unroll
    for (int it = 0; it < 2; ++it) {
        const int item = tid + it * 256;
        const int pp = item >> 5, g = item & 31;
        const float* fr = f + pp * 768 + g;
        float acc[9];
        #pragma unroll
        for (int o = 0; o < 9; ++o) acc[o] = bsh[o];
        #pragma unroll
        for (int c = 0; c < 24; ++c) {
            float v = fr[c * 32];
            #pragma unroll
            for (int o = 0; o < 9; ++o) acc[o] += w[o][c] * v;
        }
        #pragma unroll
        for (int o = 0; o < 9; ++o) ob[pp][g * 9 + o] = acc[o];
    }
    __syncthreads();
    float* og = fconv + (size_t)b * 288 * HWP + p0;
    for (int i = tid; i < 288 * 16; i += 256) {
        int ch = i >> 4, pp = i & 15;
        og[(size_t)ch * HWP + pp] = ob[pp][ch];
    }
}

// ---------------------------------------------------------------------------
// Kernel C: grouped 3x3 conv (pad 1). Writes rate2 * conv to d_out (NCHW).
__global__ __launch_bounds__(256) void conv_kernel(const float* __restrict__ fconv,
                                                   const float* __restrict__ dep_w,
                                                   const float* __restrict__ rate2p,
                                                   float* __restrict__ out) {
    __shared__ float tile[9][16][16];
    __shared__ float wsh[8][9][9];
    const int tid = threadIdx.x;
    const int t = blockIdx.x;
    const int ty0 = (t >> 2) * 14, tx0 = (t & 3) * 14;
    const int g = blockIdx.y, b = blockIdx.z;
    for (int i = tid; i < 648; i += 256) {
        int c8 = i / 81, rest = i % 81;
        wsh[c8][rest / 9][rest % 9] = dep_w[(size_t)(g * 8 + c8) * 81 + rest];
    }
    const float* fp = fconv + ((size_t)b * 288 + g * 9) * HWP;
    for (int i = tid; i < 9 * 256; i += 256) {
        int o = i >> 8, rr = i & 255;
        int yy = ty0 - 1 + (rr >> 4), xx = tx0 - 1 + (rr & 15);
        float v = 0.f;
        if (yy >= 0 && yy < HH && xx >= 0 && xx < WW)
            v = fp[(size_t)o * HWP + yy * WW + xx];
        tile[o][rr >> 4][rr & 15] = v;
    }
    __syncthreads();
    if (tid < 196) {
        const int ly = tid / 14, lx = tid % 14;
        float acc[8] = {};
        #pragma unroll
        for (int o = 0; o < 9; ++o)
            #pragma unroll
            for (int ky = 0; ky < 3; ++ky)
                #pragma unroll
                for (int kx = 0; kx < 3; ++kx) {
                    float v = tile[o][ly + ky][lx + kx];
                    #pragma unroll
                    for (int c8 = 0; c8 < 8; ++c8)
                        acc[c8] += v * wsh[c8][o][ky * 3 + kx];
                }
        const float r2 = rate2p[0];
        const int y = ty0 + ly, xcol = tx0 + lx;
        #pragma unroll
        for (int c8 = 0; c8 < 8; ++c8)
            out[((size_t)b * DIM + g * 8 + c8) * HWP + y * WW + xcol] = r2 * acc[c8];
    }
}

// ---------------------------------------------------------------------------
// Kernel D (MFMA flash-style): one block = one window, 8 waves = 8 heads.
// S = (Q K^T)*scale + bias, wave-parallel softmax, O = P V, all via
// mfma_f32_16x16x32_bf16 with 49 padded to 64.
__global__ __launch_bounds__(512) void attn_kernel(const float* __restrict__ qkv,
                                                   const float* __restrict__ rpb,
                                                   float* __restrict__ obuf) {
    __shared__ __attribute__((aligned(16))) short VT[256 * 72];  // [h*32+d][m] 36 KB
    __shared__ __attribute__((aligned(16))) short PL[8 * 16 * 72]; // per-wave [16][72] 18 KB
    const int tid = threadIdx.x;
    const int win = blockIdx.x;
    const int b = win >> 6, wrw = win & 63;
    const int wy = wrw >> 3, wx = wrw & 7;
    const size_t wbase = (size_t)b * HWP + (size_t)(wy * 7) * WW + wx * 7; // window origin pixel

    // ---- stage V transposed: VT[h*32+d][m], pad m>=49 with 0 ----
    {
        const int m = tid & 63;
        const int mq = div7(m), mr = m - mq * 7;
        const float* vrow = qkv + (wbase + mq * WW + mr) * NQKV + 512;
        for (int R = tid >> 6; R < 256; R += 8) {
            float v = (m < 49) ? vrow[R] : 0.f;
            VT[R * 72 + m] = f2bf(v);
        }
    }

    const int lane = tid & 63;
    const int h = tid >> 6;               // wave = head
    const int c = lane & 15, qg = lane >> 4;

    // ---- Q A-frags and K B-frags direct from global (rows clamped to 48) ----
    short8 aq[4], bk[4];
    #pragma unroll
    for (int f = 0; f < 4; ++f) {
        int t = f * 16 + c; if (t > 48) t = 48;
        const int tq = div7(t), tr = t - tq * 7;
        const float* base = qkv + (wbase + tq * WW + tr) * NQKV + h * 32 + qg * 8;
        float4 q0 = *(const float4*)base;
        float4 q1 = *(const float4*)(base + 4);
        short8 sq, sk;
        sq[0]=f2bf(q0.x); sq[1]=f2bf(q0.y); sq[2]=f2bf(q0.z); sq[3]=f2bf(q0.w);
        sq[4]=f2bf(q1.x); sq[5]=f2bf(q1.y); sq[6]=f2bf(q1.z); sq[7]=f2bf(q1.w);
        aq[f] = sq;
        float4 k0 = *(const float4*)(base + 256);
        float4 k1 = *(const float4*)(base + 260);
        sk[0]=f2bf(k0.x); sk[1]=f2bf(k0.y); sk[2]=f2bf(k0.z); sk[3]=f2bf(k0.w);
        sk[4]=f2bf(k1.x); sk[5]=f2bf(k1.y); sk[6]=f2bf(k1.z); sk[7]=f2bf(k1.w);
        bk[f] = sk;
    }
    __syncthreads();

    // ---- V B-frags from LDS (reused across fm blocks) ----
    short8 bv[2][2];
    #pragma unroll
    for (int ks = 0; ks < 2; ++ks)
        #pragma unroll
        for (int fo = 0; fo < 2; ++fo)
            bv[ks][fo] = *(const short8*)&VT[(h * 32 + fo * 16 + c) * 72 + ks * 32 + qg * 8];

    const float scale = 0.17677669529663687f;
    short* pw = PL + h * 16 * 72;

    #pragma unroll
    for (int fm = 0; fm < 4; ++fm) {
        // S block: rows 16*fm..+15, all 64 cols
        f32x4 s[4];
        #pragma unroll
        for (int fj = 0; fj < 4; ++fj)
            s[fj] = __builtin_amdgcn_mfma_f32_16x16x32_bf16(aq[fm], bk[fj],
                                                            (f32x4){0.f,0.f,0.f,0.f}, 0, 0, 0);
        // bias + scale + mask -> p[fj][reg]
        float p[4][4];
        #pragma unroll
        for (int reg = 0; reg < 4; ++reg) {
            int n = fm * 16 + qg * 4 + reg; int nc = n > 48 ? 48 : n;
            int nd = div7(nc), nm = nc - nd * 7;
            #pragma unroll
            for (int fj = 0; fj < 4; ++fj) {
                int mm = fj * 16 + c;
                float bias;
                if (mm < 49) {
                    int md = div7(mm), mmod = mm - md * 7;
                    int idx = (nd - md + 6) * 13 + (nm - mmod + 6);
                    bias = rpb[idx * NHEADS + h];
                } else bias = -1e30f;
                p[fj][reg] = s[fj][reg] * scale + bias;
            }
        }
        // wave-parallel softmax over 64 cols (4 fj x 16 lanes)
        float inv[4];
        #pragma unroll
        for (int reg = 0; reg < 4; ++reg) {
            float mx = fmaxf(fmaxf(p[0][reg], p[1][reg]), fmaxf(p[2][reg], p[3][reg]));
            mx = fmaxf(mx, __shfl_xor(mx, 1));
            mx = fmaxf(mx, __shfl_xor(mx, 2));
            mx = fmaxf(mx, __shfl_xor(mx, 4));
            mx = fmaxf(mx, __shfl_xor(mx, 8));
            float sum = 0.f;
            #pragma unroll
            for (int fj = 0; fj < 4; ++fj) {
                float e = __expf(p[fj][reg] - mx);
                p[fj][reg] = e; sum += e;
            }
            sum += __shfl_xor(sum, 1);
            sum += __shfl_xor(sum, 2);
            sum += __shfl_xor(sum, 4);
            sum += __shfl_xor(sum, 8);
            inv[reg] = 1.0f / sum;
        }
        // normalize, pack pairs via shfl_xor(1), write PL rows (even lanes)
        #pragma unroll
        for (int fj = 0; fj < 4; ++fj)
            #pragma unroll
            for (int reg = 0; reg < 4; ++reg) {
                float v = p[fj][reg] * inv[reg];
                float o = __shfl_xor(v, 1);
                unsigned packed = (c & 1) ? pack2bf(o, v) : pack2bf(v, o);
                if ((c & 1) == 0)
                    *(unsigned*)&pw[(qg * 4 + reg) * 72 + fj * 16 + c] = packed;
            }
        // PV for this 16-row block (A-frags from private PL; no barrier needed)
        short8 ap0 = *(const short8*)&pw[c * 72 + 0 * 32 + qg * 8];
        short8 ap1 = *(const short8*)&pw[c * 72 + 1 * 32 + qg * 8];
        #pragma unroll
        for (int fo = 0; fo < 2; ++fo) {
            f32x4 o4 = __builtin_amdgcn_mfma_f32_16x16x32_bf16(ap0, bv[0][fo],
                                                               (f32x4){0.f,0.f,0.f,0.f}, 0, 0, 0);
            o4 = __builtin_amdgcn_mfma_f32_16x16x32_bf16(ap1, bv[1][fo], o4, 0, 0, 0);
            #pragma unroll
            for (int reg = 0; reg < 4; ++reg) {
                int n = fm * 16 + qg * 4 + reg;
                if (n < 49) {
                    int nd = div7(n), nm = n - nd * 7;
                    obuf[(wbase + nd * WW + nm) * DIM + h * 32 + fo * 16 + c] = o4[reg];
                }
            }
        }
    }
}

// ---------------------------------------------------------------------------
// Kernel E: proj GEMM + combine.  out[b,c,p] += rate1 * (obuf @ proj_w^T + pb)
__global__ __launch_bounds__(256) void proj_gemm(const float* __restrict__ obuf,
                                                 const float* __restrict__ pw,
                                                 const float* __restrict__ pb,
                                                 const float* __restrict__ rate1p,
                                                 float* __restrict__ out) {
    __shared__ float As[16][64];
    __shared__ float Bs[16][64];
    __shared__ float Ct[64][65];
    const int m0 = blockIdx.x * 64;
    const int c0 = blockIdx.y * 64;
    const int tid = threadIdx.x;
    const int tx = tid & 15, ty = tid >> 4;
    float acc[4][4] = {};
    const int mm = tid >> 2, kq4 = (tid & 3) * 4;
    for (int k0 = 0; k0 < DIM; k0 += 16) {
        float4 a = *(const float4*)&obuf[(size_t)(m0 + mm) * DIM + k0 + kq4];
        As[kq4 + 0][mm] = a.x; As[kq4 + 1][mm] = a.y;
        As[kq4 + 2][mm] = a.z; As[kq4 + 3][mm] = a.w;
        float4 bb = *(const float4*)&pw[(size_t)(c0 + mm) * DIM + k0 + kq4];
        Bs[kq4 + 0][mm] = bb.x; Bs[kq4 + 1][mm] = bb.y;
        Bs[kq4 + 2][mm] = bb.z; Bs[kq4 + 3][mm] = bb.w;
        __syncthreads();
        #pragma unroll
        for (int kk = 0; kk < 16; ++kk) {
            float a_[4], b_[4];
            #pragma unroll
            for (int i = 0; i < 4; ++i) a_[i] = As[kk][ty * 4 + i];
            #pragma unroll
            for (int j = 0; j < 4; ++j) b_[j] = Bs[kk][tx * 4 + j];
            #pragma unroll
            for (int i = 0; i < 4; ++i)
                #pragma unroll
                for (int j = 0; j < 4; ++j) acc[i][j] += a_[i] * b_[j];
        }
        __syncthreads();
    }
    #pragma unroll
    for (int i = 0; i < 4; ++i)
        #pragma unroll
        for (int j = 0; j < 4; ++j)
            Ct[tx * 4 + j][ty * 4 + i] = acc[i][j] + pb[c0 + tx * 4 + j];
    __syncthreads();
    const float r1 = rate1p[0];
    const int b = m0 / HWP, p0 = m0 % HWP;
    float* ob = out + (size_t)b * DIM * HWP + p0;
    for (int i = tid; i < 64 * 64; i += 256) {
        int cl = i >> 6, ml = i & 63;
        float* dst = ob + (size_t)(c0 + cl) * HWP + ml;
        *dst = *dst + r1 * Ct[cl][ml];
    }
}

// ---------------------------------------------------------------------------
extern "C" void kernel_launch(void* const* d_in, const int* in_sizes, int n_in,
                              void* d_out, int out_size, void* d_ws, size_t ws_size,
                              hipStream_t stream) {
    const float* x      = (const float*)d_in[0];
    const float* qkv_w  = (const float*)d_in[1];
    const float* qkv_b  = (const float*)d_in[2];
    const float* fc_w   = (const float*)d_in[3];
    const float* fc_b   = (const float*)d_in[4];
    const float* dep_w  = (const float*)d_in[5];
    const float* proj_w = (const float*)d_in[6];
    const float* proj_b = (const float*)d_in[7];
    const float* rpb    = (const float*)d_in[8];
    const float* rate1  = (const float*)d_in[9];
    const float* rate2  = (const float*)d_in[10];
    float* out = (float*)d_out;

    float* qkv   = (float*)d_ws;
    float* fconv = (float*)((char*)d_ws + QKV_BYTES);
    float* obuf  = fconv;  // reused after conv_kernel consumes fconv

    qkv_gemm<<<dim3(2352), 256, 0, stream>>>(x, qkv_w, qkv_b, qkv);
    fc_kernel<<<dim3(HWP / 16, BATCH), 256, 0, stream>>>(qkv, fc_w, fc_b, fconv);
    conv_kernel<<<dim3(16, 32, BATCH), 256, 0, stream>>>(fconv, dep_w, rate2, out);
    attn_kernel<<<dim3(1024), 512, 0, stream>>>(qkv, rpb, obuf);
    proj_gemm<<<dim3(M_TOT / 64, DIM / 64), 256, 0, stream>>>(obuf, proj_w, proj_b, rate1, out);
}

// Round 5
// 364.221 us; speedup vs baseline: 3.1317x; 1.0874x over previous
//
#include <hip/hip_runtime.h>

// Problem constants (B=16, DIM=256, H=W=56, NH=8, HD=32, WS=7)
#define BATCH 16
#define DIM 256
#define HH 56
#define WW 56
#define HWP 3136            // 56*56
#define M_TOT 50176         // BATCH*HWP
#define NQKV 768            // 3*DIM
#define NHEADS 8
#define HDIM 32
#define NWIN 49             // 7*7
#define QKV_BYTES 154140672ull  // M_TOT*NQKV*4

typedef float f32x4 __attribute__((ext_vector_type(4)));
typedef short short8 __attribute__((ext_vector_type(8)));

__device__ __forceinline__ short f2bf(float f) {
    unsigned u = __float_as_uint(f);
    u += 0x7fffu + ((u >> 16) & 1u);   // RNE
    return (short)(u >> 16);
}
__device__ __forceinline__ unsigned pack2bf(float lo, float hi) {
    unsigned ul = __float_as_uint(lo); ul += 0x7fffu + ((ul >> 16) & 1u);
    unsigned uh = __float_as_uint(hi); uh += 0x7fffu + ((uh >> 16) & 1u);
    return (ul >> 16) | (uh & 0xffff0000u);
}
__device__ __forceinline__ int div7(int n) { return (n * 9363) >> 16; }  // exact for 0..63

// ---------------------------------------------------------------------------
// Kernel A (MFMA): qkv[m][j] = sum_k x^T[k][m] * wq[k][j] + bq[j]
__global__ __launch_bounds__(256) void qkv_gemm(const float* __restrict__ x,
                                                const float* __restrict__ wq,
                                                const float* __restrict__ bq,
                                                float* __restrict__ qkv) {
    __shared__ short A_lds[128 * 64];
    __shared__ short B_lds[128 * 64];
    const int bidx = blockIdx.x;
    const int wg = (bidx & 7) * 294 + (bidx >> 3);
    const int jt = wg % 6, mt = wg / 6;
    const int m0 = mt * 128, j0 = jt * 128;

    const int tid = threadIdx.x;
    const int lane = tid & 63;
    const int wave = tid >> 6;
    const int wr = wave >> 1, wc = wave & 1;

    const int srow = tid & 127;
    const int kh = tid >> 7;
    const int gm = m0 + srow;
    const int sb = gm / HWP, sp = gm % HWP;
    const float* aptr = x + ((size_t)sb * DIM + kh * 32) * HWP + sp;
    const float* bptr = wq + (size_t)(kh * 32) * NQKV + j0 + srow;

    f32x4 acc[4][4];
    #pragma unroll
    for (int i = 0; i < 4; ++i)
        #pragma unroll
        for (int j = 0; j < 4; ++j) acc[i][j] = (f32x4){0.f, 0.f, 0.f, 0.f};

    const int r = lane & 15, q = lane >> 4;
    for (int k0 = 0; k0 < DIM; k0 += 64) {
        __syncthreads();
        const float* ap = aptr + (size_t)k0 * HWP;
        #pragma unroll
        for (int g = 0; g < 4; ++g) {
            short8 s;
            #pragma unroll
            for (int i = 0; i < 8; ++i) s[i] = f2bf(ap[(size_t)(g * 8 + i) * HWP]);
            *(short8*)&A_lds[srow * 64 + 8 * ((kh * 4 + g) ^ (srow & 7))] = s;
        }
        const float* bp = bptr + (size_t)k0 * NQKV;
        #pragma unroll
        for (int g = 0; g < 4; ++g) {
            short8 s;
            #pragma unroll
            for (int i = 0; i < 8; ++i) s[i] = f2bf(bp[(size_t)(g * 8 + i) * NQKV]);
            *(short8*)&B_lds[srow * 64 + 8 * ((kh * 4 + g) ^ (srow & 7))] = s;
        }
        __syncthreads();
        #pragma unroll
        for (int ks = 0; ks < 2; ++ks) {
            short8 af[4], bfr[4];
            #pragma unroll
            for (int f = 0; f < 4; ++f) {
                int mrow = wr * 64 + f * 16 + r;
                af[f] = *(const short8*)&A_lds[mrow * 64 + 8 * ((ks * 4 + q) ^ (mrow & 7))];
                int nrow = wc * 64 + f * 16 + r;
                bfr[f] = *(const short8*)&B_lds[nrow * 64 + 8 * ((ks * 4 + q) ^ (nrow & 7))];
            }
            #pragma unroll
            for (int fm = 0; fm < 4; ++fm)
                #pragma unroll
                for (int fj = 0; fj < 4; ++fj)
                    acc[fm][fj] = __builtin_amdgcn_mfma_f32_16x16x32_bf16(
                        af[fm], bfr[fj], acc[fm][fj], 0, 0, 0);
        }
    }
    #pragma unroll
    for (int fm = 0; fm < 4; ++fm) {
        const int mbase = m0 + wr * 64 + fm * 16 + q * 4;
        #pragma unroll
        for (int fj = 0; fj < 4; ++fj) {
            const int j = j0 + wc * 64 + fj * 16 + r;
            const float bias = bq[j];
            float* op = qkv + (size_t)mbase * NQKV + j;
            #pragma unroll
            for (int rg = 0; rg < 4; ++rg)
                op[(size_t)rg * NQKV] = acc[fm][fj][rg] + bias;
        }
    }
}

// ---------------------------------------------------------------------------
// Kernel B: f_conv[b, g*9+o, p] = sum_c fc_w[o,c]*qkv[b,p,c*32+g] + fc_b[o]
__global__ __launch_bounds__(256) void fc_kernel(const float* __restrict__ qkv,
                                                 const float* __restrict__ fc_w,
                                                 const float* __restrict__ fc_b,
                                                 float* __restrict__ fconv) {
    __shared__ float f[16 * 768];
    __shared__ float ob[16][289];
    __shared__ float w[9][24];
    __shared__ float bsh[9];
    const int tid = threadIdx.x;
    if (tid < 216) w[tid / 24][tid % 24] = fc_w[tid];
    if (tid < 9) bsh[tid] = fc_b[tid];
    const int p0 = blockIdx.x * 16;
    const int b  = blockIdx.y;
    const float4* src = (const float4*)(qkv + ((size_t)b * HWP + p0) * NQKV);
    float4* dstf = (float4*)f;
    #pragma unroll
    for (int i = 0; i < 12; ++i) dstf[tid + i * 256] = src[tid + i * 256];
    __syncthreads();
    #pragma unroll
    for (int it = 0; it < 2; ++it) {
        const int item = tid + it * 256;
        const int pp = item >> 5, g = item & 31;
        const float* fr = f + pp * 768 + g;
        float acc[9];
        #pragma unroll
        for (int o = 0; o < 9; ++o) acc[o] = bsh[o];
        #pragma unroll
        for (int c = 0; c < 24; ++c) {
            float v = fr[c * 32];
            #pragma unroll
            for (int o = 0; o < 9; ++o) acc[o] += w[o][c] * v;
        }
        #pragma unroll
        for (int o = 0; o < 9; ++o) ob[pp][g * 9 + o] = acc[o];
    }
    __syncthreads();
    float* og = fconv + (size_t)b * 288 * HWP + p0;
    for (int i = tid; i < 288 * 16; i += 256) {
        int ch = i >> 4, pp = i & 15;
        og[(size_t)ch * HWP + pp] = ob[pp][ch];
    }
}

// ---------------------------------------------------------------------------
// Kernel C: grouped 3x3 conv (pad 1). Writes rate2 * conv to d_out (NCHW).
__global__ __launch_bounds__(256) void conv_kernel(const float* __restrict__ fconv,
                                                   const float* __restrict__ dep_w,
                                                   const float* __restrict__ rate2p,
                                                   float* __restrict__ out) {
    __shared__ float tile[9][16][16];
    __shared__ float wsh[8][9][9];
    const int tid = threadIdx.x;
    const int t = blockIdx.x;
    const int ty0 = (t >> 2) * 14, tx0 = (t & 3) * 14;
    const int g = blockIdx.y, b = blockIdx.z;
    for (int i = tid; i < 648; i += 256) {
        int c8 = i / 81, rest = i % 81;
        wsh[c8][rest / 9][rest % 9] = dep_w[(size_t)(g * 8 + c8) * 81 + rest];
    }
    const float* fp = fconv + ((size_t)b * 288 + g * 9) * HWP;
    for (int i = tid; i < 9 * 256; i += 256) {
        int o = i >> 8, rr = i & 255;
        int yy = ty0 - 1 + (rr >> 4), xx = tx0 - 1 + (rr & 15);
        float v = 0.f;
        if (yy >= 0 && yy < HH && xx >= 0 && xx < WW)
            v = fp[(size_t)o * HWP + yy * WW + xx];
        tile[o][rr >> 4][rr & 15] = v;
    }
    __syncthreads();
    if (tid < 196) {
        const int ly = tid / 14, lx = tid % 14;
        float acc[8] = {};
        #pragma unroll
        for (int o = 0; o < 9; ++o)
            #pragma unroll
            for (int ky = 0; ky < 3; ++ky)
                #pragma unroll
                for (int kx = 0; kx < 3; ++kx) {
                    float v = tile[o][ly + ky][lx + kx];
                    #pragma unroll
                    for (int c8 = 0; c8 < 8; ++c8)
                        acc[c8] += v * wsh[c8][o][ky * 3 + kx];
                }
        const float r2 = rate2p[0];
        const int y = ty0 + ly, xcol = tx0 + lx;
        #pragma unroll
        for (int c8 = 0; c8 < 8; ++c8)
            out[((size_t)b * DIM + g * 8 + c8) * HWP + y * WW + xcol] = r2 * acc[c8];
    }
}

// ---------------------------------------------------------------------------
// Kernel D (MFMA flash-style): one block = one window, 8 waves = 8 heads.
__global__ __launch_bounds__(512) void attn_kernel(const float* __restrict__ qkv,
                                                   const float* __restrict__ rpb,
                                                   float* __restrict__ obuf) {
    __shared__ __attribute__((aligned(16))) short VT[256 * 72];  // [h*32+d][m] 36 KB
    __shared__ __attribute__((aligned(16))) short PL[8 * 16 * 72]; // per-wave [16][72] 18 KB
    const int tid = threadIdx.x;
    const int win = blockIdx.x;
    const int b = win >> 6, wrw = win & 63;
    const int wy = wrw >> 3, wx = wrw & 7;
    const size_t wbase = (size_t)b * HWP + (size_t)(wy * 7) * WW + wx * 7;

    {
        const int m = tid & 63;
        const int mq = div7(m), mr = m - mq * 7;
        const float* vrow = qkv + (wbase + mq * WW + mr) * NQKV + 512;
        for (int R = tid >> 6; R < 256; R += 8) {
            float v = (m < 49) ? vrow[R] : 0.f;
            VT[R * 72 + m] = f2bf(v);
        }
    }

    const int lane = tid & 63;
    const int h = tid >> 6;
    const int c = lane & 15, qg = lane >> 4;

    short8 aq[4], bk[4];
    #pragma unroll
    for (int f = 0; f < 4; ++f) {
        int t = f * 16 + c; if (t > 48) t = 48;
        const int tq = div7(t), tr = t - tq * 7;
        const float* base = qkv + (wbase + tq * WW + tr) * NQKV + h * 32 + qg * 8;
        float4 q0 = *(const float4*)base;
        float4 q1 = *(const float4*)(base + 4);
        short8 sq, sk;
        sq[0]=f2bf(q0.x); sq[1]=f2bf(q0.y); sq[2]=f2bf(q0.z); sq[3]=f2bf(q0.w);
        sq[4]=f2bf(q1.x); sq[5]=f2bf(q1.y); sq[6]=f2bf(q1.z); sq[7]=f2bf(q1.w);
        aq[f] = sq;
        float4 k0 = *(const float4*)(base + 256);
        float4 k1 = *(const float4*)(base + 260);
        sk[0]=f2bf(k0.x); sk[1]=f2bf(k0.y); sk[2]=f2bf(k0.z); sk[3]=f2bf(k0.w);
        sk[4]=f2bf(k1.x); sk[5]=f2bf(k1.y); sk[6]=f2bf(k1.z); sk[7]=f2bf(k1.w);
        bk[f] = sk;
    }
    __syncthreads();

    short8 bv[2][2];
    #pragma unroll
    for (int ks = 0; ks < 2; ++ks)
        #pragma unroll
        for (int fo = 0; fo < 2; ++fo)
            bv[ks][fo] = *(const short8*)&VT[(h * 32 + fo * 16 + c) * 72 + ks * 32 + qg * 8];

    const float scale = 0.17677669529663687f;
    short* pw = PL + h * 16 * 72;

    #pragma unroll
    for (int fm = 0; fm < 4; ++fm) {
        f32x4 s[4];
        #pragma unroll
        for (int fj = 0; fj < 4; ++fj)
            s[fj] = __builtin_amdgcn_mfma_f32_16x16x32_bf16(aq[fm], bk[fj],
                                                            (f32x4){0.f,0.f,0.f,0.f}, 0, 0, 0);
        float p[4][4];
        #pragma unroll
        for (int reg = 0; reg < 4; ++reg) {
            int n = fm * 16 + qg * 4 + reg; int nc = n > 48 ? 48 : n;
            int nd = div7(nc), nm = nc - nd * 7;
            #pragma unroll
            for (int fj = 0; fj < 4; ++fj) {
                int mm = fj * 16 + c;
                float bias;
                if (mm < 49) {
                    int md = div7(mm), mmod = mm - md * 7;
                    int idx = (nd - md + 6) * 13 + (nm - mmod + 6);
                    bias = rpb[idx * NHEADS + h];
                } else bias = -1e30f;
                p[fj][reg] = s[fj][reg] * scale + bias;
            }
        }
        float inv[4];
        #pragma unroll
        for (int reg = 0; reg < 4; ++reg) {
            float mx = fmaxf(fmaxf(p[0][reg], p[1][reg]), fmaxf(p[2][reg], p[3][reg]));
            mx = fmaxf(mx, __shfl_xor(mx, 1));
            mx = fmaxf(mx, __shfl_xor(mx, 2));
            mx = fmaxf(mx, __shfl_xor(mx, 4));
            mx = fmaxf(mx, __shfl_xor(mx, 8));
            float sum = 0.f;
            #pragma unroll
            for (int fj = 0; fj < 4; ++fj) {
                float e = __expf(p[fj][reg] - mx);
                p[fj][reg] = e; sum += e;
            }
            sum += __shfl_xor(sum, 1);
            sum += __shfl_xor(sum, 2);
            sum += __shfl_xor(sum, 4);
            sum += __shfl_xor(sum, 8);
            inv[reg] = 1.0f / sum;
        }
        #pragma unroll
        for (int fj = 0; fj < 4; ++fj)
            #pragma unroll
            for (int reg = 0; reg < 4; ++reg) {
                float v = p[fj][reg] * inv[reg];
                float o = __shfl_xor(v, 1);
                unsigned packed = (c & 1) ? pack2bf(o, v) : pack2bf(v, o);
                if ((c & 1) == 0)
                    *(unsigned*)&pw[(qg * 4 + reg) * 72 + fj * 16 + c] = packed;
            }
        short8 ap0 = *(const short8*)&pw[c * 72 + 0 * 32 + qg * 8];
        short8 ap1 = *(const short8*)&pw[c * 72 + 1 * 32 + qg * 8];
        #pragma unroll
        for (int fo = 0; fo < 2; ++fo) {
            f32x4 o4 = __builtin_amdgcn_mfma_f32_16x16x32_bf16(ap0, bv[0][fo],
                                                               (f32x4){0.f,0.f,0.f,0.f}, 0, 0, 0);
            o4 = __builtin_amdgcn_mfma_f32_16x16x32_bf16(ap1, bv[1][fo], o4, 0, 0, 0);
            #pragma unroll
            for (int reg = 0; reg < 4; ++reg) {
                int n = fm * 16 + qg * 4 + reg;
                if (n < 49) {
                    int nd = div7(n), nm = n - nd * 7;
                    obuf[(wbase + nd * WW + nm) * DIM + h * 32 + fo * 16 + c] = o4[reg];
                }
            }
        }
    }
}

// ---------------------------------------------------------------------------
// Kernel E (v2, MFMA): out[b,c,p] += rate1 * (obuf @ proj_w^T + pb)
// A-role = proj_w c-rows, B-role = obuf m-rows so C/D col dim = m (pixel)
// -> contiguous 16-float runs per lane-group on the NCHW RMW epilogue.
__global__ __launch_bounds__(256) void proj_gemm(const float* __restrict__ obuf,
                                                 const float* __restrict__ pwm,
                                                 const float* __restrict__ pb,
                                                 const float* __restrict__ rate1p,
                                                 float* __restrict__ out) {
    __shared__ short M_lds[128 * 64];   // obuf m-rows [row][64k] swizzled
    __shared__ short C_lds[128 * 64];   // proj_w c-rows
    const int bidx = blockIdx.x;
    const int wg = (bidx & 7) * 98 + (bidx >> 3);   // grid 784 = 8*98
    const int ct = wg & 1, mt = wg >> 1;
    const int m0 = mt * 128, c0 = ct * 128;

    const int tid = threadIdx.x;
    const int lane = tid & 63;
    const int wave = tid >> 6;
    const int wr = wave >> 1, wc = wave & 1;   // wr: c-half, wc: m-half

    const int srow = tid & 127;
    const int kh = tid >> 7;
    const float* mptr = obuf + (size_t)(m0 + srow) * DIM + kh * 32;
    const float* cptr = pwm  + (size_t)(c0 + srow) * DIM + kh * 32;

    f32x4 acc[4][4];
    #pragma unroll
    for (int i = 0; i < 4; ++i)
        #pragma unroll
        for (int j = 0; j < 4; ++j) acc[i][j] = (f32x4){0.f, 0.f, 0.f, 0.f};

    const int r = lane & 15, q = lane >> 4;
    for (int k0 = 0; k0 < DIM; k0 += 64) {
        __syncthreads();
        #pragma unroll
        for (int g = 0; g < 4; ++g) {
            float4 v0 = *(const float4*)(mptr + k0 + g * 8);
            float4 v1 = *(const float4*)(mptr + k0 + g * 8 + 4);
            short8 s;
            s[0]=f2bf(v0.x); s[1]=f2bf(v0.y); s[2]=f2bf(v0.z); s[3]=f2bf(v0.w);
            s[4]=f2bf(v1.x); s[5]=f2bf(v1.y); s[6]=f2bf(v1.z); s[7]=f2bf(v1.w);
            *(short8*)&M_lds[srow * 64 + 8 * ((kh * 4 + g) ^ (srow & 7))] = s;
            float4 w0 = *(const float4*)(cptr + k0 + g * 8);
            float4 w1 = *(const float4*)(cptr + k0 + g * 8 + 4);
            short8 t;
            t[0]=f2bf(w0.x); t[1]=f2bf(w0.y); t[2]=f2bf(w0.z); t[3]=f2bf(w0.w);
            t[4]=f2bf(w1.x); t[5]=f2bf(w1.y); t[6]=f2bf(w1.z); t[7]=f2bf(w1.w);
            *(short8*)&C_lds[srow * 64 + 8 * ((kh * 4 + g) ^ (srow & 7))] = t;
        }
        __syncthreads();
        #pragma unroll
        for (int ks = 0; ks < 2; ++ks) {
            short8 cf[4], mf[4];
            #pragma unroll
            for (int f = 0; f < 4; ++f) {
                int crow = wr * 64 + f * 16 + r;
                cf[f] = *(const short8*)&C_lds[crow * 64 + 8 * ((ks * 4 + q) ^ (crow & 7))];
                int mrow = wc * 64 + f * 16 + r;
                mf[f] = *(const short8*)&M_lds[mrow * 64 + 8 * ((ks * 4 + q) ^ (mrow & 7))];
            }
            #pragma unroll
            for (int fc = 0; fc < 4; ++fc)
                #pragma unroll
                for (int fm2 = 0; fm2 < 4; ++fm2)
                    acc[fc][fm2] = __builtin_amdgcn_mfma_f32_16x16x32_bf16(
                        cf[fc], mf[fm2], acc[fc][fm2], 0, 0, 0);
        }
    }
    // epilogue: col r = m, row q*4+reg = c.  out[(b*DIM+c)*HWP + p] RMW.
    const float r1 = rate1p[0];
    size_t boff[4];
    #pragma unroll
    for (int fm2 = 0; fm2 < 4; ++fm2) {
        int mb = m0 + wc * 64 + fm2 * 16 + r;
        boff[fm2] = (size_t)(mb / HWP) * DIM * HWP + (mb % HWP);
    }
    #pragma unroll
    for (int fc = 0; fc < 4; ++fc) {
        #pragma unroll
        for (int reg = 0; reg < 4; ++reg) {
            const int cc = c0 + wr * 64 + fc * 16 + q * 4 + reg;
            const float bias = pb[cc];
            #pragma unroll
            for (int fm2 = 0; fm2 < 4; ++fm2) {
                float* dst = out + boff[fm2] + (size_t)cc * HWP;
                *dst = *dst + r1 * (acc[fc][fm2][reg] + bias);
            }
        }
    }
}

// ---------------------------------------------------------------------------
extern "C" void kernel_launch(void* const* d_in, const int* in_sizes, int n_in,
                              void* d_out, int out_size, void* d_ws, size_t ws_size,
                              hipStream_t stream) {
    const float* x      = (const float*)d_in[0];
    const float* qkv_w  = (const float*)d_in[1];
    const float* qkv_b  = (const float*)d_in[2];
    const float* fc_w   = (const float*)d_in[3];
    const float* fc_b   = (const float*)d_in[4];
    const float* dep_w  = (const float*)d_in[5];
    const float* proj_w = (const float*)d_in[6];
    const float* proj_b = (const float*)d_in[7];
    const float* rpb    = (const float*)d_in[8];
    const float* rate1  = (const float*)d_in[9];
    const float* rate2  = (const float*)d_in[10];
    float* out = (float*)d_out;

    float* qkv   = (float*)d_ws;
    float* fconv = (float*)((char*)d_ws + QKV_BYTES);
    float* obuf  = fconv;  // reused after conv_kernel consumes fconv

    qkv_gemm<<<dim3(2352), 256, 0, stream>>>(x, qkv_w, qkv_b, qkv);
    fc_kernel<<<dim3(HWP / 16, BATCH), 256, 0, stream>>>(qkv, fc_w, fc_b, fconv);
    conv_kernel<<<dim3(16, 32, BATCH), 256, 0, stream>>>(fconv, dep_w, rate2, out);
    attn_kernel<<<dim3(1024), 512, 0, stream>>>(qkv, rpb, obuf);
    proj_gemm<<<dim3(784), 256, 0, stream>>>(obuf, proj_w, proj_b, rate1, out);
}

// Round 6
// 290.075 us; speedup vs baseline: 3.9322x; 1.2556x over previous
//
#include <hip/hip_runtime.h>

// Problem constants (B=16, DIM=256, H=W=56, NH=8, HD=32, WS=7)
#define BATCH 16
#define DIM 256
#define HH 56
#define WW 56
#define HWP 3136            // 56*56
#define M_TOT 50176         // BATCH*HWP
#define NQKV 768            // 3*DIM
#define NHEADS 8
#define HDIM 32
#define NWIN 49             // 7*7
#define QKV_BYTES 77070336ull   // M_TOT*NQKV*2 (bf16)

typedef float f32x4 __attribute__((ext_vector_type(4)));
typedef short short8 __attribute__((ext_vector_type(8)));

__device__ __forceinline__ short f2bf(float f) {
    unsigned u = __float_as_uint(f);
    u += 0x7fffu + ((u >> 16) & 1u);   // RNE
    return (short)(u >> 16);
}
__device__ __forceinline__ float bf2f(unsigned short u) {
    return __uint_as_float(((unsigned)u) << 16);
}
__device__ __forceinline__ unsigned pack2bf(float lo, float hi) {
    unsigned ul = __float_as_uint(lo); ul += 0x7fffu + ((ul >> 16) & 1u);
    unsigned uh = __float_as_uint(hi); uh += 0x7fffu + ((uh >> 16) & 1u);
    return (ul >> 16) | (uh & 0xffff0000u);
}
__device__ __forceinline__ int div7(int n) { return (n * 9363) >> 16; }  // exact for 0..63

// ---------------------------------------------------------------------------
// Kernel A (MFMA): qkv[m][j] = sum_k x^T[k][m] * wq[k][j] + bq[j]  (bf16 out)
__global__ __launch_bounds__(256) void qkv_gemm(const float* __restrict__ x,
                                                const float* __restrict__ wq,
                                                const float* __restrict__ bq,
                                                unsigned short* __restrict__ qkv) {
    __shared__ short A_lds[128 * 64];
    __shared__ short B_lds[128 * 64];
    const int bidx = blockIdx.x;
    const int wg = (bidx & 7) * 294 + (bidx >> 3);
    const int jt = wg % 6, mt = wg / 6;
    const int m0 = mt * 128, j0 = jt * 128;

    const int tid = threadIdx.x;
    const int lane = tid & 63;
    const int wave = tid >> 6;
    const int wr = wave >> 1, wc = wave & 1;

    const int srow = tid & 127;
    const int kh = tid >> 7;
    const int gm = m0 + srow;
    const int sb = gm / HWP, sp = gm % HWP;
    const float* aptr = x + ((size_t)sb * DIM + kh * 32) * HWP + sp;
    const float* bptr = wq + (size_t)(kh * 32) * NQKV + j0 + srow;

    f32x4 acc[4][4];
    #pragma unroll
    for (int i = 0; i < 4; ++i)
        #pragma unroll
        for (int j = 0; j < 4; ++j) acc[i][j] = (f32x4){0.f, 0.f, 0.f, 0.f};

    const int r = lane & 15, q = lane >> 4;
    for (int k0 = 0; k0 < DIM; k0 += 64) {
        __syncthreads();
        const float* ap = aptr + (size_t)k0 * HWP;
        #pragma unroll
        for (int g = 0; g < 4; ++g) {
            short8 s;
            #pragma unroll
            for (int i = 0; i < 8; ++i) s[i] = f2bf(ap[(size_t)(g * 8 + i) * HWP]);
            *(short8*)&A_lds[srow * 64 + 8 * ((kh * 4 + g) ^ (srow & 7))] = s;
        }
        const float* bp = bptr + (size_t)k0 * NQKV;
        #pragma unroll
        for (int g = 0; g < 4; ++g) {
            short8 s;
            #pragma unroll
            for (int i = 0; i < 8; ++i) s[i] = f2bf(bp[(size_t)(g * 8 + i) * NQKV]);
            *(short8*)&B_lds[srow * 64 + 8 * ((kh * 4 + g) ^ (srow & 7))] = s;
        }
        __syncthreads();
        #pragma unroll
        for (int ks = 0; ks < 2; ++ks) {
            short8 af[4], bfr[4];
            #pragma unroll
            for (int f = 0; f < 4; ++f) {
                int mrow = wr * 64 + f * 16 + r;
                af[f] = *(const short8*)&A_lds[mrow * 64 + 8 * ((ks * 4 + q) ^ (mrow & 7))];
                int nrow = wc * 64 + f * 16 + r;
                bfr[f] = *(const short8*)&B_lds[nrow * 64 + 8 * ((ks * 4 + q) ^ (nrow & 7))];
            }
            #pragma unroll
            for (int fm = 0; fm < 4; ++fm)
                #pragma unroll
                for (int fj = 0; fj < 4; ++fj)
                    acc[fm][fj] = __builtin_amdgcn_mfma_f32_16x16x32_bf16(
                        af[fm], bfr[fj], acc[fm][fj], 0, 0, 0);
        }
    }
    #pragma unroll
    for (int fm = 0; fm < 4; ++fm) {
        const int mbase = m0 + wr * 64 + fm * 16 + q * 4;
        #pragma unroll
        for (int fj = 0; fj < 4; ++fj) {
            const int j = j0 + wc * 64 + fj * 16 + r;
            const float bias = bq[j];
            unsigned short* op = qkv + (size_t)mbase * NQKV + j;
            #pragma unroll
            for (int rg = 0; rg < 4; ++rg)
                op[(size_t)rg * NQKV] = (unsigned short)f2bf(acc[fm][fj][rg] + bias);
        }
    }
}

// ---------------------------------------------------------------------------
// Kernel B: f_conv[b, g*9+o, p] = sum_c fc_w[o,c]*bf2f(qkv[b,p,c*32+g]) + fc_b[o]
__global__ __launch_bounds__(256) void fc_kernel(const unsigned short* __restrict__ qkv,
                                                 const float* __restrict__ fc_w,
                                                 const float* __restrict__ fc_b,
                                                 float* __restrict__ fconv) {
    __shared__ unsigned short f[16 * 768];   // 24 KB
    __shared__ float ob[16][289];
    __shared__ float w[9][24];
    __shared__ float bsh[9];
    const int tid = threadIdx.x;
    if (tid < 216) w[tid / 24][tid % 24] = fc_w[tid];
    if (tid < 9) bsh[tid] = fc_b[tid];
    const int p0 = blockIdx.x * 16;
    const int b  = blockIdx.y;
    const uint4* src = (const uint4*)(qkv + ((size_t)b * HWP + p0) * NQKV);
    uint4* dstf = (uint4*)f;
    #pragma unroll
    for (int i = 0; i < 6; ++i) dstf[tid + i * 256] = src[tid + i * 256];
    __syncthreads();
    #pragma unroll
    for (int it = 0; it < 2; ++it) {
        const int item = tid + it * 256;
        const int pp = item >> 5, g = item & 31;
        const unsigned short* fr = f + pp * 768 + g;
        float acc[9];
        #pragma unroll
        for (int o = 0; o < 9; ++o) acc[o] = bsh[o];
        #pragma unroll
        for (int c = 0; c < 24; ++c) {
            float v = bf2f(fr[c * 32]);
            #pragma unroll
            for (int o = 0; o < 9; ++o) acc[o] += w[o][c] * v;
        }
        #pragma unroll
        for (int o = 0; o < 9; ++o) ob[pp][g * 9 + o] = acc[o];
    }
    __syncthreads();
    float* og = fconv + (size_t)b * 288 * HWP + p0;
    for (int i = tid; i < 288 * 16; i += 256) {
        int ch = i >> 4, pp = i & 15;
        og[(size_t)ch * HWP + pp] = ob[pp][ch];
    }
}

// ---------------------------------------------------------------------------
// Kernel C: grouped 3x3 conv (pad 1). Writes rate2 * conv to d_out (NCHW).
__global__ __launch_bounds__(256) void conv_kernel(const float* __restrict__ fconv,
                                                   const float* __restrict__ dep_w,
                                                   const float* __restrict__ rate2p,
                                                   float* __restrict__ out) {
    __shared__ float tile[9][16][16];
    __shared__ float wsh[8][9][9];
    const int tid = threadIdx.x;
    const int t = blockIdx.x;
    const int ty0 = (t >> 2) * 14, tx0 = (t & 3) * 14;
    const int g = blockIdx.y, b = blockIdx.z;
    for (int i = tid; i < 648; i += 256) {
        int c8 = i / 81, rest = i % 81;
        wsh[c8][rest / 9][rest % 9] = dep_w[(size_t)(g * 8 + c8) * 81 + rest];
    }
    const float* fp = fconv + ((size_t)b * 288 + g * 9) * HWP;
    for (int i = tid; i < 9 * 256; i += 256) {
        int o = i >> 8, rr = i & 255;
        int yy = ty0 - 1 + (rr >> 4), xx = tx0 - 1 + (rr & 15);
        float v = 0.f;
        if (yy >= 0 && yy < HH && xx >= 0 && xx < WW)
            v = fp[(size_t)o * HWP + yy * WW + xx];
        tile[o][rr >> 4][rr & 15] = v;
    }
    __syncthreads();
    if (tid < 196) {
        const int ly = tid / 14, lx = tid % 14;
        float acc[8] = {};
        #pragma unroll
        for (int o = 0; o < 9; ++o)
            #pragma unroll
            for (int ky = 0; ky < 3; ++ky)
                #pragma unroll
                for (int kx = 0; kx < 3; ++kx) {
                    float v = tile[o][ly + ky][lx + kx];
                    #pragma unroll
                    for (int c8 = 0; c8 < 8; ++c8)
                        acc[c8] += v * wsh[c8][o][ky * 3 + kx];
                }
        const float r2 = rate2p[0];
        const int y = ty0 + ly, xcol = tx0 + lx;
        #pragma unroll
        for (int c8 = 0; c8 < 8; ++c8)
            out[((size_t)b * DIM + g * 8 + c8) * HWP + y * WW + xcol] = r2 * acc[c8];
    }
}

// ---------------------------------------------------------------------------
// Kernel D (MFMA flash-style): one block = one window, 8 waves = 8 heads.
// qkv is bf16 -> Q/K frags are direct short8 loads; O written bf16.
__global__ __launch_bounds__(512) void attn_kernel(const unsigned short* __restrict__ qkv,
                                                   const float* __restrict__ rpb,
                                                   unsigned short* __restrict__ obuf) {
    __shared__ __attribute__((aligned(16))) short VT[256 * 72];  // [h*32+d][m] 36 KB
    __shared__ __attribute__((aligned(16))) short PL[8 * 16 * 72]; // per-wave [16][72] 18 KB
    const int tid = threadIdx.x;
    const int win = blockIdx.x;
    const int b = win >> 6, wrw = win & 63;
    const int wy = wrw >> 3, wx = wrw & 7;
    const size_t wbase = (size_t)b * HWP + (size_t)(wy * 7) * WW + wx * 7;

    {
        const int m = tid & 63;
        const int mq = div7(m), mr = m - mq * 7;
        const unsigned short* vrow = qkv + (wbase + mq * WW + mr) * NQKV + 512;
        for (int R = tid >> 6; R < 256; R += 8)
            VT[R * 72 + m] = (m < 49) ? (short)vrow[R] : (short)0;
    }

    const int lane = tid & 63;
    const int h = tid >> 6;
    const int c = lane & 15, qg = lane >> 4;

    short8 aq[4], bk[4];
    #pragma unroll
    for (int f = 0; f < 4; ++f) {
        int t = f * 16 + c; if (t > 48) t = 48;
        const int tq = div7(t), tr = t - tq * 7;
        const unsigned short* base = qkv + (wbase + tq * WW + tr) * NQKV + h * 32 + qg * 8;
        aq[f] = *(const short8*)base;
        bk[f] = *(const short8*)(base + 256);
    }
    __syncthreads();

    short8 bv[2][2];
    #pragma unroll
    for (int ks = 0; ks < 2; ++ks)
        #pragma unroll
        for (int fo = 0; fo < 2; ++fo)
            bv[ks][fo] = *(const short8*)&VT[(h * 32 + fo * 16 + c) * 72 + ks * 32 + qg * 8];

    const float scale = 0.17677669529663687f;
    short* pw = PL + h * 16 * 72;

    #pragma unroll
    for (int fm = 0; fm < 4; ++fm) {
        f32x4 s[4];
        #pragma unroll
        for (int fj = 0; fj < 4; ++fj)
            s[fj] = __builtin_amdgcn_mfma_f32_16x16x32_bf16(aq[fm], bk[fj],
                                                            (f32x4){0.f,0.f,0.f,0.f}, 0, 0, 0);
        float p[4][4];
        #pragma unroll
        for (int reg = 0; reg < 4; ++reg) {
            int n = fm * 16 + qg * 4 + reg; int nc = n > 48 ? 48 : n;
            int nd = div7(nc), nm = nc - nd * 7;
            #pragma unroll
            for (int fj = 0; fj < 4; ++fj) {
                int mm = fj * 16 + c;
                float bias;
                if (mm < 49) {
                    int md = div7(mm), mmod = mm - md * 7;
                    int idx = (nd - md + 6) * 13 + (nm - mmod + 6);
                    bias = rpb[idx * NHEADS + h];
                } else bias = -1e30f;
                p[fj][reg] = s[fj][reg] * scale + bias;
            }
        }
        float inv[4];
        #pragma unroll
        for (int reg = 0; reg < 4; ++reg) {
            float mx = fmaxf(fmaxf(p[0][reg], p[1][reg]), fmaxf(p[2][reg], p[3][reg]));
            mx = fmaxf(mx, __shfl_xor(mx, 1));
            mx = fmaxf(mx, __shfl_xor(mx, 2));
            mx = fmaxf(mx, __shfl_xor(mx, 4));
            mx = fmaxf(mx, __shfl_xor(mx, 8));
            float sum = 0.f;
            #pragma unroll
            for (int fj = 0; fj < 4; ++fj) {
                float e = __expf(p[fj][reg] - mx);
                p[fj][reg] = e; sum += e;
            }
            sum += __shfl_xor(sum, 1);
            sum += __shfl_xor(sum, 2);
            sum += __shfl_xor(sum, 4);
            sum += __shfl_xor(sum, 8);
            inv[reg] = 1.0f / sum;
        }
        #pragma unroll
        for (int fj = 0; fj < 4; ++fj)
            #pragma unroll
            for (int reg = 0; reg < 4; ++reg) {
                float v = p[fj][reg] * inv[reg];
                float o = __shfl_xor(v, 1);
                unsigned packed = (c & 1) ? pack2bf(o, v) : pack2bf(v, o);
                if ((c & 1) == 0)
                    *(unsigned*)&pw[(qg * 4 + reg) * 72 + fj * 16 + c] = packed;
            }
        short8 ap0 = *(const short8*)&pw[c * 72 + 0 * 32 + qg * 8];
        short8 ap1 = *(const short8*)&pw[c * 72 + 1 * 32 + qg * 8];
        #pragma unroll
        for (int fo = 0; fo < 2; ++fo) {
            f32x4 o4 = __builtin_amdgcn_mfma_f32_16x16x32_bf16(ap0, bv[0][fo],
                                                               (f32x4){0.f,0.f,0.f,0.f}, 0, 0, 0);
            o4 = __builtin_amdgcn_mfma_f32_16x16x32_bf16(ap1, bv[1][fo], o4, 0, 0, 0);
            #pragma unroll
            for (int reg = 0; reg < 4; ++reg) {
                int n = fm * 16 + qg * 4 + reg;
                if (n < 49) {
                    int nd = div7(n), nm = n - nd * 7;
                    obuf[(wbase + nd * WW + nm) * DIM + h * 32 + fo * 16 + c] =
                        (unsigned short)f2bf(o4[reg]);
                }
            }
        }
    }
}

// ---------------------------------------------------------------------------
// Kernel E (MFMA): out[b,c,p] += rate1 * (obuf @ proj_w^T + pb)
// A-role = proj_w c-rows, B-role = obuf m-rows (bf16, direct short8 staging).
__global__ __launch_bounds__(256) void proj_gemm(const unsigned short* __restrict__ obuf,
                                                 const float* __restrict__ pwm,
                                                 const float* __restrict__ pb,
                                                 const float* __restrict__ rate1p,
                                                 float* __restrict__ out) {
    __shared__ short M_lds[128 * 64];
    __shared__ short C_lds[128 * 64];
    const int bidx = blockIdx.x;
    const int wg = (bidx & 7) * 98 + (bidx >> 3);   // grid 784 = 8*98
    const int ct = wg & 1, mt = wg >> 1;
    const int m0 = mt * 128, c0 = ct * 128;

    const int tid = threadIdx.x;
    const int lane = tid & 63;
    const int wave = tid >> 6;
    const int wr = wave >> 1, wc = wave & 1;

    const int srow = tid & 127;
    const int kh = tid >> 7;
    const unsigned short* mptr = obuf + (size_t)(m0 + srow) * DIM + kh * 32;
    const float* cptr = pwm + (size_t)(c0 + srow) * DIM + kh * 32;

    f32x4 acc[4][4];
    #pragma unroll
    for (int i = 0; i < 4; ++i)
        #pragma unroll
        for (int j = 0; j < 4; ++j) acc[i][j] = (f32x4){0.f, 0.f, 0.f, 0.f};

    const int r = lane & 15, q = lane >> 4;
    for (int k0 = 0; k0 < DIM; k0 += 64) {
        __syncthreads();
        #pragma unroll
        for (int g = 0; g < 4; ++g) {
            short8 s = *(const short8*)(mptr + k0 + g * 8);
            *(short8*)&M_lds[srow * 64 + 8 * ((kh * 4 + g) ^ (srow & 7))] = s;
            float4 w0 = *(const float4*)(cptr + k0 + g * 8);
            float4 w1 = *(const float4*)(cptr + k0 + g * 8 + 4);
            short8 t;
            t[0]=f2bf(w0.x); t[1]=f2bf(w0.y); t[2]=f2bf(w0.z); t[3]=f2bf(w0.w);
            t[4]=f2bf(w1.x); t[5]=f2bf(w1.y); t[6]=f2bf(w1.z); t[7]=f2bf(w1.w);
            *(short8*)&C_lds[srow * 64 + 8 * ((kh * 4 + g) ^ (srow & 7))] = t;
        }
        __syncthreads();
        #pragma unroll
        for (int ks = 0; ks < 2; ++ks) {
            short8 cf[4], mf[4];
            #pragma unroll
            for (int f = 0; f < 4; ++f) {
                int crow = wr * 64 + f * 16 + r;
                cf[f] = *(const short8*)&C_lds[crow * 64 + 8 * ((ks * 4 + q) ^ (crow & 7))];
                int mrow = wc * 64 + f * 16 + r;
                mf[f] = *(const short8*)&M_lds[mrow * 64 + 8 * ((ks * 4 + q) ^ (mrow & 7))];
            }
            #pragma unroll
            for (int fc = 0; fc < 4; ++fc)
                #pragma unroll
                for (int fm2 = 0; fm2 < 4; ++fm2)
                    acc[fc][fm2] = __builtin_amdgcn_mfma_f32_16x16x32_bf16(
                        cf[fc], mf[fm2], acc[fc][fm2], 0, 0, 0);
        }
    }
    const float r1 = rate1p[0];
    size_t boff[4];
    #pragma unroll
    for (int fm2 = 0; fm2 < 4; ++fm2) {
        int mb = m0 + wc * 64 + fm2 * 16 + r;
        boff[fm2] = (size_t)(mb / HWP) * DIM * HWP + (mb % HWP);
    }
    #pragma unroll
    for (int fc = 0; fc < 4; ++fc) {
        #pragma unroll
        for (int reg = 0; reg < 4; ++reg) {
            const int cc = c0 + wr * 64 + fc * 16 + q * 4 + reg;
            const float bias = pb[cc];
            #pragma unroll
            for (int fm2 = 0; fm2 < 4; ++fm2) {
                float* dst = out + boff[fm2] + (size_t)cc * HWP;
                *dst = *dst + r1 * (acc[fc][fm2][reg] + bias);
            }
        }
    }
}

// ---------------------------------------------------------------------------
extern "C" void kernel_launch(void* const* d_in, const int* in_sizes, int n_in,
                              void* d_out, int out_size, void* d_ws, size_t ws_size,
                              hipStream_t stream) {
    const float* x      = (const float*)d_in[0];
    const float* qkv_w  = (const float*)d_in[1];
    const float* qkv_b  = (const float*)d_in[2];
    const float* fc_w   = (const float*)d_in[3];
    const float* fc_b   = (const float*)d_in[4];
    const float* dep_w  = (const float*)d_in[5];
    const float* proj_w = (const float*)d_in[6];
    const float* proj_b = (const float*)d_in[7];
    const float* rpb    = (const float*)d_in[8];
    const float* rate1  = (const float*)d_in[9];
    const float* rate2  = (const float*)d_in[10];
    float* out = (float*)d_out;

    unsigned short* qkv = (unsigned short*)d_ws;
    float* fconv = (float*)((char*)d_ws + QKV_BYTES);
    unsigned short* obuf = (unsigned short*)fconv;  // reused after conv consumes fconv

    qkv_gemm<<<dim3(2352), 256, 0, stream>>>(x, qkv_w, qkv_b, qkv);
    fc_kernel<<<dim3(HWP / 16, BATCH), 256, 0, stream>>>(qkv, fc_w, fc_b, fconv);
    conv_kernel<<<dim3(16, 32, BATCH), 256, 0, stream>>>(fconv, dep_w, rate2, out);
    attn_kernel<<<dim3(1024), 512, 0, stream>>>(qkv, rpb, obuf);
    proj_gemm<<<dim3(784), 256, 0, stream>>>(obuf, proj_w, proj_b, rate1, out);
}